// Round 6
// baseline (183.655 us; speedup 1.0000x reference)
//
#include <hip/hip_runtime.h>

typedef unsigned int u32;
typedef unsigned short u16;
typedef __attribute__((ext_vector_type(4))) float f32x4;
typedef __attribute__((ext_vector_type(8))) short s16x8;

#define S_LEN 2048
#define DMODEL 2048
#define NH 16
#define NKV 4
#define HD 128
#define WIN 512
// 0.125 (1/sqrt(64)) * log2(e): folds score scale + exp2-domain conversion into Q
#define QSCALE 0.18033688011112042f

__device__ __forceinline__ u16 f2bf(float f) {
  union { float f; u32 u; } v; v.f = f;
  u32 r = v.u + 0x7FFFu + ((v.u >> 16) & 1u);
  return (u16)(r >> 16);
}
__device__ __forceinline__ float bf2f(u16 h) {
  union { u32 u; float f; } v; v.u = ((u32)h) << 16;
  return v.f;
}

__device__ __forceinline__ void async16(const void* g, void* l) {
  __builtin_amdgcn_global_load_lds((const __attribute__((address_space(1))) void*)g,
                                   (__attribute__((address_space(3))) void*)l, 16, 0, 0);
}

// ---------------- prep kernels ----------------

__global__ void k_rope_table(float2* __restrict__ cs) {
  int s = blockIdx.x, d = threadIdx.x;  // d in [0,64)
  float invf = expf(-((float)(2 * d) / (float)HD) * logf(10000.0f));
  float fr = (float)s * invf;
  float sv, cv;
  sincosf(fr, &sv, &cv);
  cs[s * 64 + d] = make_float2(cv, sv);
}

__global__ void k_convert_bf16(const float* __restrict__ src, u16* __restrict__ dst, int n4) {
  int i = blockIdx.x * blockDim.x + threadIdx.x;
  if (i >= n4) return;
  float4 v = ((const float4*)src)[i];
  ushort4 o;
  o.x = f2bf(v.x); o.y = f2bf(v.y); o.z = f2bf(v.z); o.w = f2bf(v.w);
  ((ushort4*)dst)[i] = o;
}

// all 4 weight transposes in one launch. tiles: Wq 4096 | Wk 1024 | Wv 1024 | Wo 4096
__global__ __launch_bounds__(256) void k_transpose_all(const float* __restrict__ Wq,
                                                       const float* __restrict__ Wk,
                                                       const float* __restrict__ Wv,
                                                       const float* __restrict__ Wo,
                                                       u16* __restrict__ WT,
                                                       u16* __restrict__ WoT) {
  __shared__ float tile[32][33];
  const int bid = blockIdx.x;
  const float* src;
  u16* dst;
  int N, nt, kt;
  if (bid < 4096) {
    src = Wq; dst = WT; N = 2048; nt = bid & 63; kt = bid >> 6;
  } else if (bid < 5120) {
    int i = bid - 4096;
    src = Wk; dst = WT + (size_t)2048 * 2048; N = 512; nt = i & 15; kt = i >> 4;
  } else if (bid < 6144) {
    int i = bid - 5120;
    src = Wv; dst = WT + (size_t)2560 * 2048; N = 512; nt = i & 15; kt = i >> 4;
  } else {
    int i = bid - 6144;
    src = Wo; dst = WoT; N = 2048; nt = i & 63; kt = i >> 6;
  }
  const int tx = threadIdx.x & 31, ty = threadIdx.x >> 5;
  const int n0 = nt * 32, k0 = kt * 32;
#pragma unroll
  for (int i = 0; i < 4; ++i)
    tile[ty + 8 * i][tx] = src[(size_t)(k0 + ty + 8 * i) * N + n0 + tx];
  __syncthreads();
#pragma unroll
  for (int i = 0; i < 4; ++i)
    dst[(size_t)(n0 + ty + 8 * i) * 2048 + k0 + tx] = f2bf(tile[tx][ty + 8 * i]);
}

// rope in-place on kr only (Q-rope is fused into k_attn). grid exact.
__global__ void k_rope_k(u16* __restrict__ kr, const float2* __restrict__ cs) {
  int i = blockIdx.x * blockDim.x + threadIdx.x;
  int rowg = i >> 6, d = i & 63;
  int s = rowg & (S_LEN - 1);
  float2 c = cs[s * 64 + d];
  u16* p = kr + (size_t)rowg * HD;
  float a = bf2f(p[d]), b = bf2f(p[d + 64]);
  p[d]      = f2bf(a * c.x - b * c.y);
  p[d + 64] = f2bf(b * c.x + a * c.y);
}

// ---------------- GEMM ----------------
// A [M][K] bf16 row-major, BT [N][K] bf16. 64x128 tile, BK=64, 4 waves (2x2 of
// 32x64), double-buffered LDS (T3-min), chunked XCD swizzle.
// MODE 0: scatter epilogue -> qr[h][s][d], kr[h][s][d], vt[h][d][s]
// MODE 1: plain fp32 C[M][N]

template <int MODE>
__global__ __launch_bounds__(256) void k_gemm(const u16* __restrict__ A, const u16* __restrict__ BT,
                                              float* __restrict__ Cf, int K, int N,
                                              u16* __restrict__ qr, u16* __restrict__ kr,
                                              u16* __restrict__ vt) {
  // A rows 0..63, B rows 64..191; each row 64 u16 = 128B; 24KB per buffer
  __shared__ u16 S[2][192 * 64];
  const int t = threadIdx.x;
  const int l = t & 63, w = t >> 6;
  const int lg = l >> 4, ll = l & 15;

  // chunked XCD swizzle (bijective: nwg % 8 == 0 for both call sites)
  const u32 nwg = gridDim.x * gridDim.y;
  const u32 bid = blockIdx.y * gridDim.x + blockIdx.x;  // m-fastest linearization
  const u32 sid = (bid & 7u) * (nwg >> 3) + (bid >> 3);
  const int m0 = (int)(sid % gridDim.x) * 64;
  const int n0 = (int)(sid / gridDim.x) * 128;

  const int wm = (w >> 1) * 32, wn = (w & 1) * 64;

  const u16* gp[6];
  u32 lo[6];
#pragma unroll
  for (int j = 0; j < 6; ++j) {
    u32 u = (u32)t * 16u + (u32)j * 4096u;
    u32 row = u >> 7;
    u32 slot = ((u >> 4) & 7u) ^ (row & 7u);
    lo[j] = u;
    gp[j] = (row < 64 ? A + (size_t)(m0 + (int)row) * K
                      : BT + (size_t)(n0 + (int)(row - 64)) * K) + slot * 8;
  }
  auto stage = [&](int b, int k0) {
#pragma unroll
    for (int j = 0; j < 6; ++j) async16(gp[j] + k0, (char*)S[b] + lo[j]);
  };

  f32x4 acc[2][4];
#pragma unroll
  for (int i = 0; i < 2; ++i)
#pragma unroll
    for (int j = 0; j < 4; ++j) acc[i][j] = (f32x4){0.f, 0.f, 0.f, 0.f};

  stage(0, 0);
  __syncthreads();

  const int nit = K / 64;
#pragma unroll 2
  for (int it = 0; it < nit; ++it) {
    const int cur = it & 1;
    if (it + 1 < nit) stage(cur ^ 1, (it + 1) * 64);  // loads fly under compute

    s16x8 af[2][2], bq[4][2];
#pragma unroll
    for (int mt = 0; mt < 2; ++mt) {
      u32 r = (u32)(wm + mt * 16 + ll);
#pragma unroll
      for (int ks = 0; ks < 2; ++ks)
        af[mt][ks] = *(const s16x8*)((const char*)S[cur] + r * 128u +
                                     ((((u32)(ks * 4 + lg)) ^ (r & 7u)) * 16u));
    }
#pragma unroll
    for (int nt = 0; nt < 4; ++nt) {
      u32 r = (u32)(64 + wn + nt * 16 + ll);
#pragma unroll
      for (int ks = 0; ks < 2; ++ks)
        bq[nt][ks] = *(const s16x8*)((const char*)S[cur] + r * 128u +
                                     ((((u32)(ks * 4 + lg)) ^ (r & 7u)) * 16u));
    }
#pragma unroll
    for (int ks = 0; ks < 2; ++ks)
#pragma unroll
      for (int mt = 0; mt < 2; ++mt)
#pragma unroll
        for (int nt = 0; nt < 4; ++nt)
          acc[mt][nt] = __builtin_amdgcn_mfma_f32_16x16x32_bf16(af[mt][ks], bq[nt][ks],
                                                                acc[mt][nt], 0, 0, 0);
    __syncthreads();
  }

  if (MODE == 1) {
#pragma unroll
    for (int mt = 0; mt < 2; ++mt) {
      int srow = m0 + wm + mt * 16 + lg * 4;
#pragma unroll
      for (int nt = 0; nt < 4; ++nt) {
        int col = n0 + wn + nt * 16 + ll;
        f32x4 a = acc[mt][nt];
#pragma unroll
        for (int j = 0; j < 4; ++j) Cf[(size_t)(srow + j) * N + col] = a[j];
      }
    }
  } else {
#pragma unroll
    for (int nt = 0; nt < 4; ++nt) {
      int cb = n0 + wn + nt * 16;  // wave-uniform
#pragma unroll
      for (int mt = 0; mt < 2; ++mt) {
        int srow = m0 + wm + mt * 16 + lg * 4;
        f32x4 a = acc[mt][nt];
        if (cb < 2048) {
          int hh = cb >> 7, d = (cb & 127) + ll;
          u16* p = qr + ((size_t)hh * S_LEN) * HD + d;
#pragma unroll
          for (int j = 0; j < 4; ++j) p[(size_t)(srow + j) * HD] = f2bf(a[j]);
        } else if (cb < 2560) {
          int hh = (cb - 2048) >> 7, d = ((cb - 2048) & 127) + ll;
          u16* p = kr + ((size_t)hh * S_LEN) * HD + d;
#pragma unroll
          for (int j = 0; j < 4; ++j) p[(size_t)(srow + j) * HD] = f2bf(a[j]);
        } else {
          int hh = (cb - 2560) >> 7, d = ((cb - 2560) & 127) + ll;
          ushort4 pk;
          pk.x = f2bf(a[0]); pk.y = f2bf(a[1]); pk.z = f2bf(a[2]); pk.w = f2bf(a[3]);
          *(ushort4*)(vt + ((size_t)hh * HD + d) * S_LEN + srow) = pk;
        }
      }
    }
  }
}

// ---------------- attention ----------------
// Barrier-free: K (2MB) and V (2MB) are L2-resident -> read fragments directly
// from global (16B coalesced, batched per chunk for ILP). No LDS staging, no
// s_barrier anywhere; only a per-wave P^T transpose tile in LDS (lgkm-ordered).
// Q-RoPE (+QSCALE, exp2-domain fold) applied in-register at kernel start.
// No-max softmax: z = sum exp2(s) in fp32 (scores bounded), pass 2 uses
// a = exp2(s - log2 z). Masked keys -> e = 0 naturally, no pass-2 zero-fill.
__global__ __launch_bounds__(256) void k_attn(const u16* __restrict__ qr, const u16* __restrict__ kr,
                                              const u16* __restrict__ vt, const float* __restrict__ lam,
                                              const float2* __restrict__ cs, u16* __restrict__ ao) {
  __shared__ u16 P[4][16 * 72];  // per-wave P^T tile, row stride 72 u16 (144B)
  const int t = threadIdx.x;
  const int l = t & 63, w = t >> 6;
  const int lg = l >> 4, ll = l & 15;
  const int h = blockIdx.y;
  const int bq = blockIdx.x * 64;
  const int qs = bq + w * 16;
  const int hk = h >> 2;
  const int row = qs + ll;  // this lane's q row

  const u16* Qp = qr + ((size_t)h * S_LEN + qs) * HD;
  const u16* Kp = kr + (size_t)hk * S_LEN * HD;
  const u16* Vp = vt + (size_t)hk * HD * S_LEN;

  // chunk range: kbeg = bq-512 (8-aligned, covers all 4 waves' windows), 9 chunks
  const int kbeg = (bq >= 512) ? bq - 512 : 0;
  const int nch = (bq >= 512) ? 9 : (blockIdx.x + 1);

  // ---- load Q frags and apply RoPE + QSCALE in-register ----
  s16x8 qa[4];
#pragma unroll
  for (int i = 0; i < 4; ++i)
    qa[i] = *(const s16x8*)(Qp + (size_t)ll * HD + i * 32 + lg * 8);
  {
    const float4* cp4 = (const float4*)(cs + (size_t)row * 64);  // 32 float4/row
#pragma unroll
    for (int i = 0; i < 2; ++i) {
      float4 cv[4];
#pragma unroll
      for (int jj = 0; jj < 4; ++jj) cv[jj] = cp4[i * 16 + lg * 4 + jj];
      s16x8 lo = qa[i], hi = qa[i + 2];
#pragma unroll
      for (int j = 0; j < 8; ++j) {
        float cc = (j & 1) ? cv[j >> 1].z : cv[j >> 1].x;
        float ss = (j & 1) ? cv[j >> 1].w : cv[j >> 1].y;
        float a = bf2f((u16)lo[j]), b = bf2f((u16)hi[j]);
        lo[j] = (short)f2bf((a * cc - b * ss) * QSCALE);
        hi[j] = (short)f2bf((b * cc + a * ss) * QSCALE);
      }
      qa[i] = lo; qa[i + 2] = hi;
    }
  }

  const f32x4 zero = {0.f, 0.f, 0.f, 0.f};
  float z1 = 0.f, z2 = 0.f;

  // ---- pass 1: Z sums (direct L2 K reads, no barriers) ----
  for (int tc = 0; tc < nch; ++tc) {
    const int c = kbeg + tc * 64;
    s16x8 kb[4][4];
#pragma unroll
    for (int kt = 0; kt < 4; ++kt) {
      const u16* kp = Kp + (size_t)(c + kt * 16 + ll) * HD + lg * 8;
#pragma unroll
      for (int i = 0; i < 4; ++i) kb[kt][i] = *(const s16x8*)(kp + i * 32);
    }
    const bool full = (c + 63 <= qs) && (c >= qs - 496);  // wave-uniform
    float acc1 = 0.f, acc2 = 0.f;
#pragma unroll
    for (int kt = 0; kt < 4; ++kt) {
      f32x4 a = __builtin_amdgcn_mfma_f32_16x16x32_bf16(kb[kt][0], qa[0], zero, 0, 0, 0);
      a = __builtin_amdgcn_mfma_f32_16x16x32_bf16(kb[kt][1], qa[1], a, 0, 0, 0);
      f32x4 b = __builtin_amdgcn_mfma_f32_16x16x32_bf16(kb[kt][2], qa[2], zero, 0, 0, 0);
      b = __builtin_amdgcn_mfma_f32_16x16x32_bf16(kb[kt][3], qa[3], b, 0, 0, 0);
      if (!full) {
#pragma unroll
        for (int j = 0; j < 4; ++j) {
          int key = c + kt * 16 + lg * 4 + j;
          bool ok = (key <= row) && (key > row - WIN);
          a[j] = ok ? a[j] : -1e30f;
          b[j] = ok ? b[j] : -1e30f;
        }
      }
#pragma unroll
      for (int j = 0; j < 4; ++j) {
        acc1 += __builtin_amdgcn_exp2f(a[j]);  // exp2(-1e30) flushes to 0
        acc2 += __builtin_amdgcn_exp2f(b[j]);
      }
    }
    z1 += acc1; z2 += acc2;
  }

  // merge the 4 lg-group partials (lanes ll, ll+16, ll+32, ll+48 share q=ll)
  z1 += __shfl_xor(z1, 16, 64); z1 += __shfl_xor(z1, 32, 64);
  z2 += __shfl_xor(z2, 16, 64); z2 += __shfl_xor(z2, 32, 64);
  const float l2z1 = __builtin_amdgcn_logf(z1);  // v_log_f32 = log2
  const float l2z2 = __builtin_amdgcn_logf(z2);
  const float lm = lam[h];

  // ---- pass 2: recompute scores, diff-combine, PV (direct L2, no barriers) ----
  f32x4 o[8];
#pragma unroll
  for (int dt = 0; dt < 8; ++dt) o[dt] = zero;
  float dsum = 0.f;
  u16* Pw = &P[w][0];

  for (int tc = 0; tc < nch; ++tc) {
    const int c = kbeg + tc * 64;
    s16x8 kb[4][4];
#pragma unroll
    for (int kt = 0; kt < 4; ++kt) {
      const u16* kp = Kp + (size_t)(c + kt * 16 + ll) * HD + lg * 8;
#pragma unroll
      for (int i = 0; i < 4; ++i) kb[kt][i] = *(const s16x8*)(kp + i * 32);
    }
    f32x4 sa[4], sb[4];
#pragma unroll
    for (int kt = 0; kt < 4; ++kt) {
      f32x4 a = __builtin_amdgcn_mfma_f32_16x16x32_bf16(kb[kt][0], qa[0], zero, 0, 0, 0);
      a = __builtin_amdgcn_mfma_f32_16x16x32_bf16(kb[kt][1], qa[1], a, 0, 0, 0);
      f32x4 b = __builtin_amdgcn_mfma_f32_16x16x32_bf16(kb[kt][2], qa[2], zero, 0, 0, 0);
      b = __builtin_amdgcn_mfma_f32_16x16x32_bf16(kb[kt][3], qa[3], b, 0, 0, 0);
      sa[kt] = a; sb[kt] = b;
    }
    // V frags issued here: latency hides under the exp/pack VALU phase below
    s16x8 vf[8][2];
#pragma unroll
    for (int dt = 0; dt < 8; ++dt) {
      const u16* vp = Vp + (size_t)(dt * 16 + ll) * S_LEN + c + lg * 8;
      vf[dt][0] = *(const s16x8*)(vp);
      vf[dt][1] = *(const s16x8*)(vp + 32);
    }
    const bool full = (c + 63 <= qs) && (c >= qs - 496);
#pragma unroll
    for (int kt = 0; kt < 4; ++kt) {
      f32x4 a = sa[kt], b = sb[kt];
      if (!full) {
#pragma unroll
        for (int j = 0; j < 4; ++j) {
          int key = c + kt * 16 + lg * 4 + j;
          bool ok = (key <= row) && (key > row - WIN);
          a[j] = ok ? a[j] : -1e30f;
          b[j] = ok ? b[j] : -1e30f;
        }
      }
      float d4[4];
#pragma unroll
      for (int j = 0; j < 4; ++j) {
        float a1 = __builtin_amdgcn_exp2f(a[j] - l2z1);
        float a2 = __builtin_amdgcn_exp2f(b[j] - l2z2);
        float d = fmaxf(fmaf(-lm, a2, a1), 0.f);
        d4[j] = d;
        dsum += d;
      }
      u32 p01, p23;
      asm("v_cvt_pk_bf16_f32 %0, %1, %2" : "=v"(p01) : "v"(d4[0]), "v"(d4[1]));
      asm("v_cvt_pk_bf16_f32 %0, %1, %2" : "=v"(p23) : "v"(d4[2]), "v"(d4[3]));
      uint2 pk; pk.x = p01; pk.y = p23;
      *(uint2*)(&Pw[ll * 72 + kt * 16 + lg * 4]) = pk;
    }
    // per-wave LDS transpose round-trip (wave-synchronous; compiler waits lgkm)
    s16x8 pf0 = *(const s16x8*)(&Pw[ll * 72 + lg * 8]);
    s16x8 pf1 = *(const s16x8*)(&Pw[ll * 72 + 32 + lg * 8]);
#pragma unroll
    for (int dt = 0; dt < 8; ++dt) {
      o[dt] = __builtin_amdgcn_mfma_f32_16x16x32_bf16(pf0, vf[dt][0], o[dt], 0, 0, 0);
      o[dt] = __builtin_amdgcn_mfma_f32_16x16x32_bf16(pf1, vf[dt][1], o[dt], 0, 0, 0);
    }
  }

  // dsum: merge lg partials, then fetch 1/(sum+eps) for output rows lg*4+j
  dsum += __shfl_xor(dsum, 16, 64);
  dsum += __shfl_xor(dsum, 32, 64);
  const float rds = __builtin_amdgcn_rcpf(dsum + 1e-6f);
  float rdsj[4];
#pragma unroll
  for (int j = 0; j < 4; ++j) rdsj[j] = __shfl(rds, lg * 4 + j, 64);

#pragma unroll
  for (int dt = 0; dt < 8; ++dt) {
#pragma unroll
    for (int j = 0; j < 4; ++j) {
      int srow = qs + lg * 4 + j;
      ao[(size_t)srow * DMODEL + h * HD + dt * 16 + ll] = f2bf(o[dt][j] * rdsj[j]);
    }
  }
}

// ---------------- launch ----------------

extern "C" void kernel_launch(void* const* d_in, const int* in_sizes, int n_in,
                              void* d_out, int out_size, void* d_ws, size_t ws_size,
                              hipStream_t stream) {
  const float* x = (const float*)d_in[0];
  const float* Wq = (const float*)d_in[1];
  const float* Wk = (const float*)d_in[2];
  const float* Wv = (const float*)d_in[3];
  const float* Wo = (const float*)d_in[4];
  const float* lam = (const float*)d_in[5];
  float* out = (float*)d_out;

  char* ws = (char*)d_ws;
  u16* xb = (u16*)(ws);                               // 8 MB  [2048][2048]
  u16* WT = (u16*)(ws + (8u << 20));                  // 12 MB [3072][2048] (Wq^T|Wk^T|Wv^T)
  u16* WoT = (u16*)(ws + (20u << 20));                // 8 MB  [2048][2048]
  u16* qr = (u16*)(ws + (28u << 20));                 // 8 MB  [16][2048][128]
  u16* kr = (u16*)(ws + (36u << 20));                 // 2 MB  [4][2048][128]
  u16* vt = (u16*)(ws + (38u << 20));                 // 2 MB  [4][128][2048]
  u16* ao = (u16*)(ws + (40u << 20));                 // 8 MB  [2048][2048]
  float2* cs = (float2*)(ws + (48u << 20));           // 1 MB  [2048][64]

  k_rope_table<<<S_LEN, 64, 0, stream>>>(cs);
  k_convert_bf16<<<4096, 256, 0, stream>>>(x, xb, (S_LEN * DMODEL) / 4);

  k_transpose_all<<<10240, 256, 0, stream>>>(Wq, Wk, Wv, Wo, WT, WoT);

  k_gemm<0><<<dim3(32, 24), 256, 0, stream>>>(xb, WT, nullptr, 2048, 3072, qr, kr, vt);

  // K roped in-place; Q-rope (+QSCALE) is fused into k_attn
  k_rope_k<<<(NKV * S_LEN * 64) / 256, 256, 0, stream>>>(kr, cs);

  k_attn<<<dim3(S_LEN / 64, NH), 256, 0, stream>>>(qr, kr, vt, lam, cs, ao);

  k_gemm<1><<<dim3(32, 16), 256, 0, stream>>>(ao, WoT, out, 2048, 2048, nullptr, nullptr, nullptr);
}

// Round 7
// 123.890 us; speedup vs baseline: 1.4824x; 1.4824x over previous
//
#include <hip/hip_runtime.h>

typedef unsigned int u32;
typedef unsigned short u16;
typedef __attribute__((ext_vector_type(4))) float f32x4;
typedef __attribute__((ext_vector_type(8))) short s16x8;

#define S_LEN 2048
#define DMODEL 2048
#define NH 16
#define NKV 4
#define HD 128
#define WIN 512
// 0.125 (1/sqrt(64)) * log2(e): folds score scale + exp2-domain conversion into Q
#define QSCALE 0.18033688011112042f

__device__ __forceinline__ u16 f2bf(float f) {
  union { float f; u32 u; } v; v.f = f;
  u32 r = v.u + 0x7FFFu + ((v.u >> 16) & 1u);
  return (u16)(r >> 16);
}
__device__ __forceinline__ float bf2f(u16 h) {
  union { u32 u; float f; } v; v.u = ((u32)h) << 16;
  return v.f;
}

__device__ __forceinline__ void async16(const void* g, void* l) {
  __builtin_amdgcn_global_load_lds((const __attribute__((address_space(1))) void*)g,
                                   (__attribute__((address_space(3))) void*)l, 16, 0, 0);
}

// ---------------- prep kernels ----------------

__global__ void k_rope_table(float2* __restrict__ cs) {
  int s = blockIdx.x, d = threadIdx.x;  // d in [0,64)
  float invf = expf(-((float)(2 * d) / (float)HD) * logf(10000.0f));
  float fr = (float)s * invf;
  float sv, cv;
  sincosf(fr, &sv, &cv);
  cs[s * 64 + d] = make_float2(cv, sv);
}

__global__ void k_convert_bf16(const float* __restrict__ src, u16* __restrict__ dst, int n4) {
  int i = blockIdx.x * blockDim.x + threadIdx.x;
  if (i >= n4) return;
  float4 v = ((const float4*)src)[i];
  ushort4 o;
  o.x = f2bf(v.x); o.y = f2bf(v.y); o.z = f2bf(v.z); o.w = f2bf(v.w);
  ((ushort4*)dst)[i] = o;
}

// all 4 weight transposes in one launch. tiles: Wq 4096 | Wk 1024 | Wv 1024 | Wo 4096
__global__ __launch_bounds__(256) void k_transpose_all(const float* __restrict__ Wq,
                                                       const float* __restrict__ Wk,
                                                       const float* __restrict__ Wv,
                                                       const float* __restrict__ Wo,
                                                       u16* __restrict__ WT,
                                                       u16* __restrict__ WoT) {
  __shared__ float tile[32][33];
  const int bid = blockIdx.x;
  const float* src;
  u16* dst;
  int N, nt, kt;
  if (bid < 4096) {
    src = Wq; dst = WT; N = 2048; nt = bid & 63; kt = bid >> 6;
  } else if (bid < 5120) {
    int i = bid - 4096;
    src = Wk; dst = WT + (size_t)2048 * 2048; N = 512; nt = i & 15; kt = i >> 4;
  } else if (bid < 6144) {
    int i = bid - 5120;
    src = Wv; dst = WT + (size_t)2560 * 2048; N = 512; nt = i & 15; kt = i >> 4;
  } else {
    int i = bid - 6144;
    src = Wo; dst = WoT; N = 2048; nt = i & 63; kt = i >> 6;
  }
  const int tx = threadIdx.x & 31, ty = threadIdx.x >> 5;
  const int n0 = nt * 32, k0 = kt * 32;
#pragma unroll
  for (int i = 0; i < 4; ++i)
    tile[ty + 8 * i][tx] = src[(size_t)(k0 + ty + 8 * i) * N + n0 + tx];
  __syncthreads();
#pragma unroll
  for (int i = 0; i < 4; ++i)
    dst[(size_t)(n0 + ty + 8 * i) * 2048 + k0 + tx] = f2bf(tile[tx][ty + 8 * i]);
}

// rope on q (scaled by QSCALE) and k (scale 1) in one launch.
__global__ void k_rope_apply2(u16* __restrict__ qr, u16* __restrict__ kr,
                              const float2* __restrict__ cs) {
  int i = blockIdx.x * blockDim.x + threadIdx.x;
  int rowg = i >> 6, d = i & 63;
  const bool isq = rowg < NH * S_LEN;
  u16* p = isq ? qr + (size_t)rowg * HD : kr + (size_t)(rowg - NH * S_LEN) * HD;
  const float scale = isq ? QSCALE : 1.0f;
  int s = rowg & (S_LEN - 1);
  float2 c = cs[s * 64 + d];
  float a = bf2f(p[d]), b = bf2f(p[d + 64]);
  p[d]      = f2bf((a * c.x - b * c.y) * scale);
  p[d + 64] = f2bf((b * c.x + a * c.y) * scale);
}

// ---------------- GEMM ----------------
// A [M][K] bf16 row-major, BT [N][K] bf16. 64x128 tile, BK=64, 4 waves (2x2 of
// 32x64), double-buffered LDS (T3-min), chunked XCD swizzle.
// MODE 0: scatter epilogue -> qr[h][s][d], kr[h][s][d], vt[h][d][s]
// MODE 1: plain fp32 C[M][N]

template <int MODE>
__global__ __launch_bounds__(256) void k_gemm(const u16* __restrict__ A, const u16* __restrict__ BT,
                                              float* __restrict__ Cf, int K, int N,
                                              u16* __restrict__ qr, u16* __restrict__ kr,
                                              u16* __restrict__ vt) {
  // A rows 0..63, B rows 64..191; each row 64 u16 = 128B; 24KB per buffer
  __shared__ u16 S[2][192 * 64];
  const int t = threadIdx.x;
  const int l = t & 63, w = t >> 6;
  const int lg = l >> 4, ll = l & 15;

  // chunked XCD swizzle (bijective: nwg % 8 == 0 for both call sites)
  const u32 nwg = gridDim.x * gridDim.y;
  const u32 bid = blockIdx.y * gridDim.x + blockIdx.x;  // m-fastest linearization
  const u32 sid = (bid & 7u) * (nwg >> 3) + (bid >> 3);
  const int m0 = (int)(sid % gridDim.x) * 64;
  const int n0 = (int)(sid / gridDim.x) * 128;

  const int wm = (w >> 1) * 32, wn = (w & 1) * 64;

  const u16* gp[6];
  u32 lo[6];
#pragma unroll
  for (int j = 0; j < 6; ++j) {
    u32 u = (u32)t * 16u + (u32)j * 4096u;
    u32 row = u >> 7;
    u32 slot = ((u >> 4) & 7u) ^ (row & 7u);
    lo[j] = u;
    gp[j] = (row < 64 ? A + (size_t)(m0 + (int)row) * K
                      : BT + (size_t)(n0 + (int)(row - 64)) * K) + slot * 8;
  }
  auto stage = [&](int b, int k0) {
#pragma unroll
    for (int j = 0; j < 6; ++j) async16(gp[j] + k0, (char*)S[b] + lo[j]);
  };

  f32x4 acc[2][4];
#pragma unroll
  for (int i = 0; i < 2; ++i)
#pragma unroll
    for (int j = 0; j < 4; ++j) acc[i][j] = (f32x4){0.f, 0.f, 0.f, 0.f};

  stage(0, 0);
  __syncthreads();

  const int nit = K / 64;
#pragma unroll 2
  for (int it = 0; it < nit; ++it) {
    const int cur = it & 1;
    if (it + 1 < nit) stage(cur ^ 1, (it + 1) * 64);  // loads fly under compute

    s16x8 af[2][2], bq[4][2];
#pragma unroll
    for (int mt = 0; mt < 2; ++mt) {
      u32 r = (u32)(wm + mt * 16 + ll);
#pragma unroll
      for (int ks = 0; ks < 2; ++ks)
        af[mt][ks] = *(const s16x8*)((const char*)S[cur] + r * 128u +
                                     ((((u32)(ks * 4 + lg)) ^ (r & 7u)) * 16u));
    }
#pragma unroll
    for (int nt = 0; nt < 4; ++nt) {
      u32 r = (u32)(64 + wn + nt * 16 + ll);
#pragma unroll
      for (int ks = 0; ks < 2; ++ks)
        bq[nt][ks] = *(const s16x8*)((const char*)S[cur] + r * 128u +
                                     ((((u32)(ks * 4 + lg)) ^ (r & 7u)) * 16u));
    }
#pragma unroll
    for (int ks = 0; ks < 2; ++ks)
#pragma unroll
      for (int mt = 0; mt < 2; ++mt)
#pragma unroll
        for (int nt = 0; nt < 4; ++nt)
          acc[mt][nt] = __builtin_amdgcn_mfma_f32_16x16x32_bf16(af[mt][ks], bq[nt][ks],
                                                                acc[mt][nt], 0, 0, 0);
    __syncthreads();
  }

  if (MODE == 1) {
#pragma unroll
    for (int mt = 0; mt < 2; ++mt) {
      int srow = m0 + wm + mt * 16 + lg * 4;
#pragma unroll
      for (int nt = 0; nt < 4; ++nt) {
        int col = n0 + wn + nt * 16 + ll;
        f32x4 a = acc[mt][nt];
#pragma unroll
        for (int j = 0; j < 4; ++j) Cf[(size_t)(srow + j) * N + col] = a[j];
      }
    }
  } else {
#pragma unroll
    for (int nt = 0; nt < 4; ++nt) {
      int cb = n0 + wn + nt * 16;  // wave-uniform
#pragma unroll
      for (int mt = 0; mt < 2; ++mt) {
        int srow = m0 + wm + mt * 16 + lg * 4;
        f32x4 a = acc[mt][nt];
        if (cb < 2048) {
          int hh = cb >> 7, d = (cb & 127) + ll;
          u16* p = qr + ((size_t)hh * S_LEN) * HD + d;
#pragma unroll
          for (int j = 0; j < 4; ++j) p[(size_t)(srow + j) * HD] = f2bf(a[j]);
        } else if (cb < 2560) {
          int hh = (cb - 2048) >> 7, d = ((cb - 2048) & 127) + ll;
          u16* p = kr + ((size_t)hh * S_LEN) * HD + d;
#pragma unroll
          for (int j = 0; j < 4; ++j) p[(size_t)(srow + j) * HD] = f2bf(a[j]);
        } else {
          int hh = (cb - 2560) >> 7, d = ((cb - 2560) & 127) + ll;
          ushort4 pk;
          pk.x = f2bf(a[0]); pk.y = f2bf(a[1]); pk.z = f2bf(a[2]); pk.w = f2bf(a[3]);
          *(ushort4*)(vt + ((size_t)hh * HD + d) * S_LEN + srow) = pk;
        }
      }
    }
  }
}

// ---------------- attention ----------------
// Staged (global_load_lds, block-shared, coalesced) with SMALL LDS footprint:
// 2 x 16KB buffers reused by both passes -> ~38KB/block -> 4 blocks/CU
// (16 waves/CU, 2x R5's TLP). Pass 1: KVBLK=64 K-only tiles, T3-min dbuf.
// Pass 2: KVBLK=32, each buffer = K(8KB) + V(8KB), T3-min dbuf.
// No-max softmax (scores bounded, exp2 domain); per-lane key-local scores via
// swapped mfma(K,Q); per-wave P^T transpose tile for PV.
__global__ __launch_bounds__(256, 4) void k_attn(const u16* __restrict__ qr,
                                                 const u16* __restrict__ kr,
                                                 const u16* __restrict__ vt,
                                                 const float* __restrict__ lam,
                                                 u16* __restrict__ ao) {
  __shared__ u16 KV[2][8192];   // 2 x 16KB
  __shared__ u16 P[4][16 * 40]; // per-wave P^T tile, row stride 40 u16 (80B)
  const int t = threadIdx.x;
  const int l = t & 63, w = t >> 6;
  const int lg = l >> 4, ll = l & 15;
  const int h = blockIdx.y;
  const int bq = blockIdx.x * 64;
  const int qs = bq + w * 16;
  const int hk = h >> 2;
  const int row = qs + ll;  // this lane's q row

  const u16* Qp = qr + ((size_t)h * S_LEN + qs) * HD;
  const u16* Kp = kr + (size_t)hk * S_LEN * HD;
  const u16* Vp = vt + (size_t)hk * HD * S_LEN;

  const int kbeg = (bq >= 512) ? bq - 512 : 0;
  const int nch1 = (bq >= 512) ? 9 : (bq / 64 + 1);   // 64-key chunks (pass 1)
  const int nch2 = nch1 * 2;                          // 32-key chunks (pass 2)

  // pass-1 staging coords (16KB tile: 64 rows x 256B, 16 slots, slot ^= row&7)
  u32 ku1[4], kr1[4], ks1[4];
#pragma unroll
  for (int j = 0; j < 4; ++j) {
    u32 u = (u32)t * 16u + (u32)j * 4096u;
    ku1[j] = u;
    kr1[j] = u >> 8;
    ks1[j] = ((u >> 4) & 15u) ^ (kr1[j] & 7u);
  }
  // pass-2 K coords (8KB: 32 rows x 256B) and V coords (8KB: 64 LDS rows x 128B,
  // LDS row r = d rows 2r,2r+1 each 64B; logical slot = phys ^ (r&7))
  u32 ku2[2], kr2[2], ks2[2], vu2[2], vd2[2], vk2[2];
#pragma unroll
  for (int j = 0; j < 2; ++j) {
    u32 u = (u32)t * 16u + (u32)j * 4096u;
    ku2[j] = u;
    kr2[j] = u >> 8;
    ks2[j] = ((u >> 4) & 15u) ^ (kr2[j] & 7u);
    u32 r = u >> 7;
    u32 lgc = ((u >> 4) & 7u) ^ (r & 7u);
    vu2[j] = u;
    vd2[j] = 2u * r + (lgc >> 2);
    vk2[j] = (lgc & 3u) * 8u;
  }

  // Q as B-fragment (pre-scaled by QSCALE in rope)
  s16x8 qa[4];
#pragma unroll
  for (int i = 0; i < 4; ++i)
    qa[i] = *(const s16x8*)(Qp + (size_t)ll * HD + i * 32 + lg * 8);

  const f32x4 zero = {0.f, 0.f, 0.f, 0.f};
  float z1 = 0.f, z2 = 0.f;

  // ---- pass 1: Z sums (K-only 64-key tiles, 2-buf T3-min) ----
#pragma unroll
  for (int j = 0; j < 4; ++j)
    async16(Kp + (size_t)(kbeg + kr1[j]) * HD + ks1[j] * 8, (char*)KV + ku1[j]);

  for (int tc = 0; tc < nch1; ++tc) {
    __syncthreads();  // drains vmcnt(0): chunk tc fully in LDS
    if (tc + 1 < nch1) {
      const int cn = kbeg + (tc + 1) * 64;
      char* dst = (char*)KV + (size_t)((tc + 1) & 1) * 16384;
#pragma unroll
      for (int j = 0; j < 4; ++j)
        async16(Kp + (size_t)(cn + kr1[j]) * HD + ks1[j] * 8, dst + ku1[j]);
    }
    const int c = kbeg + tc * 64;
    const bool active = (c + 63 >= qs - (WIN - 1)) && (c <= qs + 15);
    if (active) {
      const u16* Kb = (const u16*)((const char*)KV + (size_t)(tc & 1) * 16384);
      float acc1 = 0.f, acc2 = 0.f;
#pragma unroll
      for (int kt = 0; kt < 4; ++kt) {
        const int kbase = c + kt * 16;
        if (kbase > qs + 15 || kbase + 15 < qs - (WIN - 1)) continue;  // uniform
        const int kr_ = kt * 16 + ll;
        const u16* kp = Kb + kr_ * 128;
        const u32 sw = (u32)(kr_ & 7);
        s16x8 b0 = *(const s16x8*)(kp + ((lg ^ sw) * 8));
        s16x8 b1 = *(const s16x8*)(kp + (((4 + lg) ^ sw) * 8));
        s16x8 b2 = *(const s16x8*)(kp + (((8 + lg) ^ sw) * 8));
        s16x8 b3 = *(const s16x8*)(kp + (((12 + lg) ^ sw) * 8));
        f32x4 a = __builtin_amdgcn_mfma_f32_16x16x32_bf16(b0, qa[0], zero, 0, 0, 0);
        a = __builtin_amdgcn_mfma_f32_16x16x32_bf16(b1, qa[1], a, 0, 0, 0);
        f32x4 b = __builtin_amdgcn_mfma_f32_16x16x32_bf16(b2, qa[2], zero, 0, 0, 0);
        b = __builtin_amdgcn_mfma_f32_16x16x32_bf16(b3, qa[3], b, 0, 0, 0);
        const bool fullk = (kbase + 15 <= qs) && (kbase >= qs - 496);
        if (!fullk) {
#pragma unroll
          for (int j = 0; j < 4; ++j) {
            int key = kbase + lg * 4 + j;
            bool ok = (key <= row) && (key > row - WIN);
            a[j] = ok ? a[j] : -1e30f;
            b[j] = ok ? b[j] : -1e30f;
          }
        }
#pragma unroll
        for (int j = 0; j < 4; ++j) {
          acc1 += __builtin_amdgcn_exp2f(a[j]);  // exp2(-1e30) flushes to 0
          acc2 += __builtin_amdgcn_exp2f(b[j]);
        }
      }
      z1 += acc1; z2 += acc2;
    }
  }

  // merge the 4 lg-group partials (lanes ll, ll+16, ll+32, ll+48 share q=ll)
  z1 += __shfl_xor(z1, 16, 64); z1 += __shfl_xor(z1, 32, 64);
  z2 += __shfl_xor(z2, 16, 64); z2 += __shfl_xor(z2, 32, 64);
  const float l2z1 = __builtin_amdgcn_logf(z1);  // v_log_f32 = log2
  const float l2z2 = __builtin_amdgcn_logf(z2);
  const float lm = lam[h];

  // ---- pass 2: diff-combine + PV (K+V 32-key units in the same 2 buffers) ----
  f32x4 o[8];
#pragma unroll
  for (int dt = 0; dt < 8; ++dt) o[dt] = zero;
  float dsum = 0.f;
  u16* Pw = &P[w][0];

  __syncthreads();  // pass 1 compute fully done before buffers are reused
#pragma unroll
  for (int j = 0; j < 2; ++j) {
    async16(Kp + (size_t)(kbeg + kr2[j]) * HD + ks2[j] * 8, (char*)KV + ku2[j]);
    async16(Vp + (size_t)vd2[j] * S_LEN + kbeg + vk2[j], (char*)KV + 8192 + vu2[j]);
  }

  for (int tc = 0; tc < nch2; ++tc) {
    __syncthreads();  // drains vmcnt(0): chunk tc (K+V) fully in LDS
    if (tc + 1 < nch2) {
      const int cn = kbeg + (tc + 1) * 32;
      char* dst = (char*)KV + (size_t)((tc + 1) & 1) * 16384;
#pragma unroll
      for (int j = 0; j < 2; ++j) {
        async16(Kp + (size_t)(cn + kr2[j]) * HD + ks2[j] * 8, dst + ku2[j]);
        async16(Vp + (size_t)vd2[j] * S_LEN + cn + vk2[j], dst + 8192 + vu2[j]);
      }
    }
    const int c = kbeg + tc * 32;
    const bool active = (c + 31 >= qs - (WIN - 1)) && (c <= qs + 15);
    if (active) {
      const u16* Kb = (const u16*)((const char*)KV + (size_t)(tc & 1) * 16384);
      const u16* Vb = Kb + 4096;  // +8KB
      const bool full = (c + 31 <= qs) && (c >= qs - 496);
      __builtin_amdgcn_s_setprio(1);
#pragma unroll
      for (int kt = 0; kt < 2; ++kt) {
        const int kr_ = kt * 16 + ll;
        const u16* kp = Kb + kr_ * 128;
        const u32 sw = (u32)(kr_ & 7);
        s16x8 b0 = *(const s16x8*)(kp + ((lg ^ sw) * 8));
        s16x8 b1 = *(const s16x8*)(kp + (((4 + lg) ^ sw) * 8));
        s16x8 b2 = *(const s16x8*)(kp + (((8 + lg) ^ sw) * 8));
        s16x8 b3 = *(const s16x8*)(kp + (((12 + lg) ^ sw) * 8));
        f32x4 a = __builtin_amdgcn_mfma_f32_16x16x32_bf16(b0, qa[0], zero, 0, 0, 0);
        a = __builtin_amdgcn_mfma_f32_16x16x32_bf16(b1, qa[1], a, 0, 0, 0);
        f32x4 b = __builtin_amdgcn_mfma_f32_16x16x32_bf16(b2, qa[2], zero, 0, 0, 0);
        b = __builtin_amdgcn_mfma_f32_16x16x32_bf16(b3, qa[3], b, 0, 0, 0);
        if (!full) {
#pragma unroll
          for (int j = 0; j < 4; ++j) {
            int key = c + kt * 16 + lg * 4 + j;
            bool ok = (key <= row) && (key > row - WIN);
            a[j] = ok ? a[j] : -1e30f;
            b[j] = ok ? b[j] : -1e30f;
          }
        }
        float d4[4];
#pragma unroll
        for (int j = 0; j < 4; ++j) {
          float a1 = __builtin_amdgcn_exp2f(a[j] - l2z1);
          float a2 = __builtin_amdgcn_exp2f(b[j] - l2z2);
          float d = fmaxf(fmaf(-lm, a2, a1), 0.f);
          d4[j] = d;
          dsum += d;
        }
        u32 p01, p23;
        asm("v_cvt_pk_bf16_f32 %0, %1, %2" : "=v"(p01) : "v"(d4[0]), "v"(d4[1]));
        asm("v_cvt_pk_bf16_f32 %0, %1, %2" : "=v"(p23) : "v"(d4[2]), "v"(d4[3]));
        uint2 pk; pk.x = p01; pk.y = p23;
        *(uint2*)(&Pw[ll * 40 + kt * 16 + lg * 4]) = pk;
      }
      // per-wave LDS transpose round-trip (wave-synchronous; compiler waits lgkm)
      s16x8 pf = *(const s16x8*)(&Pw[ll * 40 + lg * 8]);
#pragma unroll
      for (int dt = 0; dt < 8; ++dt) {
        const int d = dt * 16 + ll;
        const u32 r = (u32)(d >> 1);
        const u32 phys = ((u32)((d & 1) * 4 + lg)) ^ (r & 7u);
        s16x8 vf = *(const s16x8*)(Vb + r * 64 + phys * 8);
        o[dt] = __builtin_amdgcn_mfma_f32_16x16x32_bf16(pf, vf, o[dt], 0, 0, 0);
      }
      __builtin_amdgcn_s_setprio(0);
    }
  }

  // dsum: merge lg partials, then fetch 1/(sum+eps) for output rows lg*4+j
  dsum += __shfl_xor(dsum, 16, 64);
  dsum += __shfl_xor(dsum, 32, 64);
  const float rds = __builtin_amdgcn_rcpf(dsum + 1e-6f);
  float rdsj[4];
#pragma unroll
  for (int j = 0; j < 4; ++j) rdsj[j] = __shfl(rds, lg * 4 + j, 64);

#pragma unroll
  for (int dt = 0; dt < 8; ++dt) {
#pragma unroll
    for (int j = 0; j < 4; ++j) {
      int srow = qs + lg * 4 + j;
      ao[(size_t)srow * DMODEL + h * HD + dt * 16 + ll] = f2bf(o[dt][j] * rdsj[j]);
    }
  }
}

// ---------------- launch ----------------

extern "C" void kernel_launch(void* const* d_in, const int* in_sizes, int n_in,
                              void* d_out, int out_size, void* d_ws, size_t ws_size,
                              hipStream_t stream) {
  const float* x = (const float*)d_in[0];
  const float* Wq = (const float*)d_in[1];
  const float* Wk = (const float*)d_in[2];
  const float* Wv = (const float*)d_in[3];
  const float* Wo = (const float*)d_in[4];
  const float* lam = (const float*)d_in[5];
  float* out = (float*)d_out;

  char* ws = (char*)d_ws;
  u16* xb = (u16*)(ws);                               // 8 MB  [2048][2048]
  u16* WT = (u16*)(ws + (8u << 20));                  // 12 MB [3072][2048] (Wq^T|Wk^T|Wv^T)
  u16* WoT = (u16*)(ws + (20u << 20));                // 8 MB  [2048][2048]
  u16* qr = (u16*)(ws + (28u << 20));                 // 8 MB  [16][2048][128]
  u16* kr = (u16*)(ws + (36u << 20));                 // 2 MB  [4][2048][128]
  u16* vt = (u16*)(ws + (38u << 20));                 // 2 MB  [4][128][2048]
  u16* ao = (u16*)(ws + (40u << 20));                 // 8 MB  [2048][2048]
  float2* cs = (float2*)(ws + (48u << 20));           // 1 MB  [2048][64]

  k_rope_table<<<S_LEN, 64, 0, stream>>>(cs);
  k_convert_bf16<<<4096, 256, 0, stream>>>(x, xb, (S_LEN * DMODEL) / 4);

  k_transpose_all<<<10240, 256, 0, stream>>>(Wq, Wk, Wv, Wo, WT, WoT);

  k_gemm<0><<<dim3(32, 24), 256, 0, stream>>>(xb, WT, nullptr, 2048, 3072, qr, kr, vt);

  // Q pre-scaled by 0.125*log2(e) -> QK^T scores land directly in exp2 domain
  k_rope_apply2<<<((NH + NKV) * S_LEN * 64) / 256, 256, 0, stream>>>(qr, kr, cs);

  k_attn<<<dim3(S_LEN / 64, NH), 256, 0, stream>>>(qr, kr, vt, lam, ao);

  k_gemm<1><<<dim3(32, 16), 256, 0, stream>>>(ao, WoT, out, 2048, 2048, nullptr, nullptr, nullptr);
}

// Round 8
// 120.102 us; speedup vs baseline: 1.5292x; 1.0315x over previous
//
#include <hip/hip_runtime.h>

typedef unsigned int u32;
typedef unsigned short u16;
typedef __attribute__((ext_vector_type(4))) float f32x4;
typedef __attribute__((ext_vector_type(8))) short s16x8;

#define S_LEN 2048
#define DMODEL 2048
#define NH 16
#define NKV 4
#define HD 128
#define WIN 512
// 0.125 (1/sqrt(64)) * log2(e): folds score scale + exp2-domain conversion into Q
#define QSCALE 0.18033688011112042f

#define WAIT_VMCNT4 asm volatile("s_waitcnt vmcnt(4)" ::: "memory")
#define WAIT_VMCNT0 asm volatile("s_waitcnt vmcnt(0)" ::: "memory")

__device__ __forceinline__ u16 f2bf(float f) {
  union { float f; u32 u; } v; v.f = f;
  u32 r = v.u + 0x7FFFu + ((v.u >> 16) & 1u);
  return (u16)(r >> 16);
}
__device__ __forceinline__ float bf2f(u16 h) {
  union { u32 u; float f; } v; v.u = ((u32)h) << 16;
  return v.f;
}

__device__ __forceinline__ void async16(const void* g, void* l) {
  __builtin_amdgcn_global_load_lds((const __attribute__((address_space(1))) void*)g,
                                   (__attribute__((address_space(3))) void*)l, 16, 0, 0);
}

// ---------------- prep kernels ----------------

__global__ void k_rope_table(float2* __restrict__ cs) {
  int s = blockIdx.x, d = threadIdx.x;  // d in [0,64)
  float invf = expf(-((float)(2 * d) / (float)HD) * logf(10000.0f));
  float fr = (float)s * invf;
  float sv, cv;
  sincosf(fr, &sv, &cv);
  cs[s * 64 + d] = make_float2(cv, sv);
}

// fused: bid<4096 -> x f32->bf16 convert; else weight transposes.
// tiles: Wq 4096 | Wk 1024 | Wv 1024 | Wo 4096
__global__ __launch_bounds__(256) void k_prep(const float* __restrict__ x, u16* __restrict__ xb,
                                              const float* __restrict__ Wq,
                                              const float* __restrict__ Wk,
                                              const float* __restrict__ Wv,
                                              const float* __restrict__ Wo,
                                              u16* __restrict__ WT, u16* __restrict__ WoT) {
  __shared__ float tile[32][33];
  const int bid = blockIdx.x;
  if (bid < 4096) {
    int i = bid * 256 + threadIdx.x;
    float4 v = ((const float4*)x)[i];
    ushort4 o;
    o.x = f2bf(v.x); o.y = f2bf(v.y); o.z = f2bf(v.z); o.w = f2bf(v.w);
    ((ushort4*)xb)[i] = o;
    return;
  }
  const int b = bid - 4096;
  const float* src;
  u16* dst;
  int N, nt, kt;
  if (b < 4096) {
    src = Wq; dst = WT; N = 2048; nt = b & 63; kt = b >> 6;
  } else if (b < 5120) {
    int i = b - 4096;
    src = Wk; dst = WT + (size_t)2048 * 2048; N = 512; nt = i & 15; kt = i >> 4;
  } else if (b < 6144) {
    int i = b - 5120;
    src = Wv; dst = WT + (size_t)2560 * 2048; N = 512; nt = i & 15; kt = i >> 4;
  } else {
    int i = b - 6144;
    src = Wo; dst = WoT; N = 2048; nt = i & 63; kt = i >> 6;
  }
  const int tx = threadIdx.x & 31, ty = threadIdx.x >> 5;
  const int n0 = nt * 32, k0 = kt * 32;
#pragma unroll
  for (int i = 0; i < 4; ++i)
    tile[ty + 8 * i][tx] = src[(size_t)(k0 + ty + 8 * i) * N + n0 + tx];
  __syncthreads();
#pragma unroll
  for (int i = 0; i < 4; ++i)
    dst[(size_t)(n0 + ty + 8 * i) * 2048 + k0 + tx] = f2bf(tile[tx][ty + 8 * i]);
}

// rope in-place on kr only (Q-rope fused into k_attn). grid exact: 2048 blocks.
__global__ void k_rope_k(u16* __restrict__ kr, const float2* __restrict__ cs) {
  int i = blockIdx.x * blockDim.x + threadIdx.x;
  int rowg = i >> 6, d = i & 63;
  int s = rowg & (S_LEN - 1);
  float2 c = cs[s * 64 + d];
  u16* p = kr + (size_t)rowg * HD;
  float a = bf2f(p[d]), b = bf2f(p[d + 64]);
  p[d]      = f2bf(a * c.x - b * c.y);
  p[d + 64] = f2bf(b * c.x + a * c.y);
}

// ---------------- GEMM ----------------
// A [M][K] bf16 row-major, BT [N][K] bf16. 64x128 tile, BK=64, 4 waves (2x2 of
// 32x64), double-buffered LDS (T3-min), chunked XCD swizzle.
// MODE 0: scatter epilogue -> qr[h][s][d], kr[h][s][d], vt[h][d][s]
// MODE 1: plain fp32 C[M][N]

template <int MODE>
__global__ __launch_bounds__(256) void k_gemm(const u16* __restrict__ A, const u16* __restrict__ BT,
                                              float* __restrict__ Cf, int K, int N,
                                              u16* __restrict__ qr, u16* __restrict__ kr,
                                              u16* __restrict__ vt) {
  // A rows 0..63, B rows 64..191; each row 64 u16 = 128B; 24KB per buffer
  __shared__ u16 S[2][192 * 64];
  const int t = threadIdx.x;
  const int l = t & 63, w = t >> 6;
  const int lg = l >> 4, ll = l & 15;

  // chunked XCD swizzle (bijective: nwg % 8 == 0 for both call sites)
  const u32 nwg = gridDim.x * gridDim.y;
  const u32 bid = blockIdx.y * gridDim.x + blockIdx.x;  // m-fastest linearization
  const u32 sid = (bid & 7u) * (nwg >> 3) + (bid >> 3);
  const int m0 = (int)(sid % gridDim.x) * 64;
  const int n0 = (int)(sid / gridDim.x) * 128;

  const int wm = (w >> 1) * 32, wn = (w & 1) * 64;

  const u16* gp[6];
  u32 lo[6];
#pragma unroll
  for (int j = 0; j < 6; ++j) {
    u32 u = (u32)t * 16u + (u32)j * 4096u;
    u32 row = u >> 7;
    u32 slot = ((u >> 4) & 7u) ^ (row & 7u);
    lo[j] = u;
    gp[j] = (row < 64 ? A + (size_t)(m0 + (int)row) * K
                      : BT + (size_t)(n0 + (int)(row - 64)) * K) + slot * 8;
  }
  auto stage = [&](int b, int k0) {
#pragma unroll
    for (int j = 0; j < 6; ++j) async16(gp[j] + k0, (char*)S[b] + lo[j]);
  };

  f32x4 acc[2][4];
#pragma unroll
  for (int i = 0; i < 2; ++i)
#pragma unroll
    for (int j = 0; j < 4; ++j) acc[i][j] = (f32x4){0.f, 0.f, 0.f, 0.f};

  stage(0, 0);
  __syncthreads();

  const int nit = K / 64;
#pragma unroll 2
  for (int it = 0; it < nit; ++it) {
    const int cur = it & 1;
    if (it + 1 < nit) stage(cur ^ 1, (it + 1) * 64);  // loads fly under compute

    s16x8 af[2][2], bq[4][2];
#pragma unroll
    for (int mt = 0; mt < 2; ++mt) {
      u32 r = (u32)(wm + mt * 16 + ll);
#pragma unroll
      for (int ks = 0; ks < 2; ++ks)
        af[mt][ks] = *(const s16x8*)((const char*)S[cur] + r * 128u +
                                     ((((u32)(ks * 4 + lg)) ^ (r & 7u)) * 16u));
    }
#pragma unroll
    for (int nt = 0; nt < 4; ++nt) {
      u32 r = (u32)(64 + wn + nt * 16 + ll);
#pragma unroll
      for (int ks = 0; ks < 2; ++ks)
        bq[nt][ks] = *(const s16x8*)((const char*)S[cur] + r * 128u +
                                     ((((u32)(ks * 4 + lg)) ^ (r & 7u)) * 16u));
    }
#pragma unroll
    for (int ks = 0; ks < 2; ++ks)
#pragma unroll
      for (int mt = 0; mt < 2; ++mt)
#pragma unroll
        for (int nt = 0; nt < 4; ++nt)
          acc[mt][nt] = __builtin_amdgcn_mfma_f32_16x16x32_bf16(af[mt][ks], bq[nt][ks],
                                                                acc[mt][nt], 0, 0, 0);
    __syncthreads();
  }

  if (MODE == 1) {
#pragma unroll
    for (int mt = 0; mt < 2; ++mt) {
      int srow = m0 + wm + mt * 16 + lg * 4;
#pragma unroll
      for (int nt = 0; nt < 4; ++nt) {
        int col = n0 + wn + nt * 16 + ll;
        f32x4 a = acc[mt][nt];
#pragma unroll
        for (int j = 0; j < 4; ++j) Cf[(size_t)(srow + j) * N + col] = a[j];
      }
    }
  } else {
#pragma unroll
    for (int nt = 0; nt < 4; ++nt) {
      int cb = n0 + wn + nt * 16;  // wave-uniform
#pragma unroll
      for (int mt = 0; mt < 2; ++mt) {
        int srow = m0 + wm + mt * 16 + lg * 4;
        f32x4 a = acc[mt][nt];
        if (cb < 2048) {
          int hh = cb >> 7, d = (cb & 127) + ll;
          u16* p = qr + ((size_t)hh * S_LEN) * HD + d;
#pragma unroll
          for (int j = 0; j < 4; ++j) p[(size_t)(srow + j) * HD] = f2bf(a[j]);
        } else if (cb < 2560) {
          int hh = (cb - 2048) >> 7, d = ((cb - 2048) & 127) + ll;
          u16* p = kr + ((size_t)hh * S_LEN) * HD + d;
#pragma unroll
          for (int j = 0; j < 4; ++j) p[(size_t)(srow + j) * HD] = f2bf(a[j]);
        } else {
          int hh = (cb - 2560) >> 7, d = ((cb - 2560) & 127) + ll;
          ushort4 pk;
          pk.x = f2bf(a[0]); pk.y = f2bf(a[1]); pk.z = f2bf(a[2]); pk.w = f2bf(a[3]);
          *(ushort4*)(vt + ((size_t)hh * HD + d) * S_LEN + srow) = pk;
        }
      }
    }
  }
}

// ---------------- attention ----------------
// Grid-limited to 2 blocks/CU (512 blocks) -> spend LDS on pipeline depth:
// BOTH passes use 4 x 16KB buffers, 2-ahead prefetch, counted vmcnt(4) + raw
// s_barrier (loads never drain to 0 in the loop; uniform clamped tail stages
// keep the per-wave vmcnt invariant exact). Pass 1: K-only 64-key tiles.
// Pass 2: 32-key tiles, each buffer = K(8KB) + V(8KB). Q-RoPE (+QSCALE fold)
// applied in-register at kernel start. No-max exp2-domain softmax.
__global__ __launch_bounds__(256, 2) void k_attn(const u16* __restrict__ qr,
                                                 const u16* __restrict__ kr,
                                                 const u16* __restrict__ vt,
                                                 const float* __restrict__ lam,
                                                 const float2* __restrict__ cs,
                                                 u16* __restrict__ ao) {
  __shared__ u16 KV[4][8192];   // 4 x 16KB
  __shared__ u16 P[4][16 * 40]; // per-wave P^T tile, row stride 40 u16 (80B)
  const int t = threadIdx.x;
  const int l = t & 63, w = t >> 6;
  const int lg = l >> 4, ll = l & 15;
  const int h = blockIdx.y;
  const int bq = blockIdx.x * 64;
  const int qs = bq + w * 16;
  const int hk = h >> 2;
  const int row = qs + ll;  // this lane's q row

  const u16* Qp = qr + ((size_t)h * S_LEN + qs) * HD;
  const u16* Kp = kr + (size_t)hk * S_LEN * HD;
  const u16* Vp = vt + (size_t)hk * HD * S_LEN;

  const int kbeg = (bq >= 512) ? bq - 512 : 0;
  const int nch1 = (bq >= 512) ? 9 : (bq / 64 + 1);   // 64-key chunks (pass 1)
  const int nch2 = nch1 * 2;                          // 32-key chunks (pass 2)

  // pass-1 staging coords (16KB tile: 64 rows x 256B, 16 slots, slot ^= row&7)
  u32 ku1[4], kr1[4], ks1[4];
#pragma unroll
  for (int j = 0; j < 4; ++j) {
    u32 u = (u32)t * 16u + (u32)j * 4096u;
    ku1[j] = u;
    kr1[j] = u >> 8;
    ks1[j] = ((u >> 4) & 15u) ^ (kr1[j] & 7u);
  }
  // pass-2 K coords (8KB: 32 rows x 256B) and V coords (8KB: 64 LDS rows x
  // 128B; LDS row r = d rows 2r,2r+1; logical slot = phys ^ (r&7))
  u32 ku2[2], kr2[2], ks2[2], vu2[2], vd2[2], vk2[2];
#pragma unroll
  for (int j = 0; j < 2; ++j) {
    u32 u = (u32)t * 16u + (u32)j * 4096u;
    ku2[j] = u;
    kr2[j] = u >> 8;
    ks2[j] = ((u >> 4) & 15u) ^ (kr2[j] & 7u);
    u32 r = u >> 7;
    u32 lgc = ((u >> 4) & 7u) ^ (r & 7u);
    vu2[j] = u;
    vd2[j] = 2u * r + (lgc >> 2);
    vk2[j] = (lgc & 3u) * 8u;
  }

  // ---- Q fragments + in-register RoPE (+QSCALE) ----
  s16x8 qa[4];
#pragma unroll
  for (int i = 0; i < 4; ++i)
    qa[i] = *(const s16x8*)(Qp + (size_t)ll * HD + i * 32 + lg * 8);
  {
    const float4* cp4 = (const float4*)(cs + (size_t)row * 64);  // 32 float4/row
#pragma unroll
    for (int i = 0; i < 2; ++i) {
      float4 cv[4];
#pragma unroll
      for (int jj = 0; jj < 4; ++jj) cv[jj] = cp4[i * 16 + lg * 4 + jj];
      s16x8 lo = qa[i], hi = qa[i + 2];
#pragma unroll
      for (int j = 0; j < 8; ++j) {
        float cc = (j & 1) ? cv[j >> 1].z : cv[j >> 1].x;
        float ss = (j & 1) ? cv[j >> 1].w : cv[j >> 1].y;
        float a = bf2f((u16)lo[j]), b = bf2f((u16)hi[j]);
        lo[j] = (short)f2bf((a * cc - b * ss) * QSCALE);
        hi[j] = (short)f2bf((b * cc + a * ss) * QSCALE);
      }
      qa[i] = lo; qa[i + 2] = hi;
    }
  }

  const f32x4 zero = {0.f, 0.f, 0.f, 0.f};
  float z1 = 0.f, z2 = 0.f;

  // ---- pass 1: Z sums (4-buf K, counted vmcnt, raw barrier) ----
  {
#pragma unroll
    for (int j = 0; j < 4; ++j)
      async16(Kp + (size_t)(kbeg + kr1[j]) * HD + ks1[j] * 8, (char*)KV + ku1[j]);
    const int c1 = kbeg + ((nch1 > 1) ? 64 : 0);
#pragma unroll
    for (int j = 0; j < 4; ++j)
      async16(Kp + (size_t)(c1 + kr1[j]) * HD + ks1[j] * 8, (char*)KV + 16384 + ku1[j]);
  }

  for (int tc = 0; tc < nch1; ++tc) {
    WAIT_VMCNT4;                    // own stage tc landed (in-order vmem)
    __builtin_amdgcn_s_barrier();   // all waves' stage tc landed
    {
      int c2i = tc + 2; if (c2i > nch1 - 1) c2i = nch1 - 1;  // clamped, uniform
      const int c2 = kbeg + c2i * 64;
      char* dst = (char*)KV + (size_t)((tc + 2) & 3) * 16384;
#pragma unroll
      for (int j = 0; j < 4; ++j)
        async16(Kp + (size_t)(c2 + kr1[j]) * HD + ks1[j] * 8, dst + ku1[j]);
    }
    const int c = kbeg + tc * 64;
    const bool active = (c + 63 >= qs - (WIN - 1)) && (c <= qs + 15);
    if (active) {
      const u16* Kb = (const u16*)((const char*)KV + (size_t)(tc & 3) * 16384);
      float acc1 = 0.f, acc2 = 0.f;
#pragma unroll
      for (int kt = 0; kt < 4; ++kt) {
        const int kbase = c + kt * 16;
        if (kbase > qs + 15 || kbase + 15 < qs - (WIN - 1)) continue;  // uniform
        const int kr_ = kt * 16 + ll;
        const u16* kp = Kb + kr_ * 128;
        const u32 sw = (u32)(kr_ & 7);
        s16x8 b0 = *(const s16x8*)(kp + ((lg ^ sw) * 8));
        s16x8 b1 = *(const s16x8*)(kp + (((4 + lg) ^ sw) * 8));
        s16x8 b2 = *(const s16x8*)(kp + (((8 + lg) ^ sw) * 8));
        s16x8 b3 = *(const s16x8*)(kp + (((12 + lg) ^ sw) * 8));
        f32x4 a = __builtin_amdgcn_mfma_f32_16x16x32_bf16(b0, qa[0], zero, 0, 0, 0);
        a = __builtin_amdgcn_mfma_f32_16x16x32_bf16(b1, qa[1], a, 0, 0, 0);
        f32x4 b = __builtin_amdgcn_mfma_f32_16x16x32_bf16(b2, qa[2], zero, 0, 0, 0);
        b = __builtin_amdgcn_mfma_f32_16x16x32_bf16(b3, qa[3], b, 0, 0, 0);
        const bool fullk = (kbase + 15 <= qs) && (kbase >= qs - 496);
        if (!fullk) {
#pragma unroll
          for (int j = 0; j < 4; ++j) {
            int key = kbase + lg * 4 + j;
            bool ok = (key <= row) && (key > row - WIN);
            a[j] = ok ? a[j] : -1e30f;
            b[j] = ok ? b[j] : -1e30f;
          }
        }
#pragma unroll
        for (int j = 0; j < 4; ++j) {
          acc1 += __builtin_amdgcn_exp2f(a[j]);  // exp2(-1e30) flushes to 0
          acc2 += __builtin_amdgcn_exp2f(b[j]);
        }
      }
      z1 += acc1; z2 += acc2;
    }
  }

  // merge the 4 lg-group partials (lanes ll, ll+16, ll+32, ll+48 share q=ll)
  z1 += __shfl_xor(z1, 16, 64); z1 += __shfl_xor(z1, 32, 64);
  z2 += __shfl_xor(z2, 16, 64); z2 += __shfl_xor(z2, 32, 64);
  const float l2z1 = __builtin_amdgcn_logf(z1);  // v_log_f32 = log2
  const float l2z2 = __builtin_amdgcn_logf(z2);
  const float lm = lam[h];

  // ---- pass 2: diff-combine + PV (4-buf K8+V8, counted vmcnt, raw barrier) ----
  f32x4 o[8];
#pragma unroll
  for (int dt = 0; dt < 8; ++dt) o[dt] = zero;
  float dsum = 0.f;
  u16* Pw = &P[w][0];

  WAIT_VMCNT0;      // pass-1 trailing stages landed
  __syncthreads();  // all waves done with pass-1 buffers

  {
#pragma unroll
    for (int j = 0; j < 2; ++j) {
      async16(Kp + (size_t)(kbeg + kr2[j]) * HD + ks2[j] * 8, (char*)KV + ku2[j]);
      async16(Vp + (size_t)vd2[j] * S_LEN + kbeg + vk2[j], (char*)KV + 8192 + vu2[j]);
    }
    const int c1 = kbeg + ((nch2 > 1) ? 32 : 0);
#pragma unroll
    for (int j = 0; j < 2; ++j) {
      async16(Kp + (size_t)(c1 + kr2[j]) * HD + ks2[j] * 8, (char*)KV + 16384 + ku2[j]);
      async16(Vp + (size_t)vd2[j] * S_LEN + c1 + vk2[j], (char*)KV + 16384 + 8192 + vu2[j]);
    }
  }

  for (int tc = 0; tc < nch2; ++tc) {
    WAIT_VMCNT4;                    // own stage tc landed
    __builtin_amdgcn_s_barrier();   // all waves' stage tc landed
    {
      int c2i = tc + 2; if (c2i > nch2 - 1) c2i = nch2 - 1;  // clamped, uniform
      const int c2 = kbeg + c2i * 32;
      char* dst = (char*)KV + (size_t)((tc + 2) & 3) * 16384;
#pragma unroll
      for (int j = 0; j < 2; ++j) {
        async16(Kp + (size_t)(c2 + kr2[j]) * HD + ks2[j] * 8, dst + ku2[j]);
        async16(Vp + (size_t)vd2[j] * S_LEN + c2 + vk2[j], dst + 8192 + vu2[j]);
      }
    }
    const int c = kbeg + tc * 32;
    const bool active = (c + 31 >= qs - (WIN - 1)) && (c <= qs + 15);
    if (active) {
      const u16* Kb = (const u16*)((const char*)KV + (size_t)(tc & 3) * 16384);
      const u16* Vb = Kb + 4096;  // +8KB
      const bool full = (c + 31 <= qs) && (c >= qs - 496);
      __builtin_amdgcn_s_setprio(1);
#pragma unroll
      for (int kt = 0; kt < 2; ++kt) {
        const int kr_ = kt * 16 + ll;
        const u16* kp = Kb + kr_ * 128;
        const u32 sw = (u32)(kr_ & 7);
        s16x8 b0 = *(const s16x8*)(kp + ((lg ^ sw) * 8));
        s16x8 b1 = *(const s16x8*)(kp + (((4 + lg) ^ sw) * 8));
        s16x8 b2 = *(const s16x8*)(kp + (((8 + lg) ^ sw) * 8));
        s16x8 b3 = *(const s16x8*)(kp + (((12 + lg) ^ sw) * 8));
        f32x4 a = __builtin_amdgcn_mfma_f32_16x16x32_bf16(b0, qa[0], zero, 0, 0, 0);
        a = __builtin_amdgcn_mfma_f32_16x16x32_bf16(b1, qa[1], a, 0, 0, 0);
        f32x4 b = __builtin_amdgcn_mfma_f32_16x16x32_bf16(b2, qa[2], zero, 0, 0, 0);
        b = __builtin_amdgcn_mfma_f32_16x16x32_bf16(b3, qa[3], b, 0, 0, 0);
        if (!full) {
#pragma unroll
          for (int j = 0; j < 4; ++j) {
            int key = c + kt * 16 + lg * 4 + j;
            bool ok = (key <= row) && (key > row - WIN);
            a[j] = ok ? a[j] : -1e30f;
            b[j] = ok ? b[j] : -1e30f;
          }
        }
        float d4[4];
#pragma unroll
        for (int j = 0; j < 4; ++j) {
          float a1 = __builtin_amdgcn_exp2f(a[j] - l2z1);
          float a2 = __builtin_amdgcn_exp2f(b[j] - l2z2);
          float d = fmaxf(fmaf(-lm, a2, a1), 0.f);
          d4[j] = d;
          dsum += d;
        }
        u32 p01, p23;
        asm("v_cvt_pk_bf16_f32 %0, %1, %2" : "=v"(p01) : "v"(d4[0]), "v"(d4[1]));
        asm("v_cvt_pk_bf16_f32 %0, %1, %2" : "=v"(p23) : "v"(d4[2]), "v"(d4[3]));
        uint2 pk; pk.x = p01; pk.y = p23;
        *(uint2*)(&Pw[ll * 40 + kt * 16 + lg * 4]) = pk;
      }
      // per-wave LDS transpose round-trip (wave-synchronous; compiler waits lgkm)
      s16x8 pf = *(const s16x8*)(&Pw[ll * 40 + lg * 8]);
#pragma unroll
      for (int dt = 0; dt < 8; ++dt) {
        const int d = dt * 16 + ll;
        const u32 r = (u32)(d >> 1);
        const u32 phys = ((u32)((d & 1) * 4 + lg)) ^ (r & 7u);
        s16x8 vf = *(const s16x8*)(Vb + r * 64 + phys * 8);
        o[dt] = __builtin_amdgcn_mfma_f32_16x16x32_bf16(pf, vf, o[dt], 0, 0, 0);
      }
      __builtin_amdgcn_s_setprio(0);
    }
  }
  WAIT_VMCNT0;  // drain trailing stages before kernel end

  // dsum: merge lg partials, then fetch 1/(sum+eps) for output rows lg*4+j
  dsum += __shfl_xor(dsum, 16, 64);
  dsum += __shfl_xor(dsum, 32, 64);
  const float rds = __builtin_amdgcn_rcpf(dsum + 1e-6f);
  float rdsj[4];
#pragma unroll
  for (int j = 0; j < 4; ++j) rdsj[j] = __shfl(rds, lg * 4 + j, 64);

#pragma unroll
  for (int dt = 0; dt < 8; ++dt) {
#pragma unroll
    for (int j = 0; j < 4; ++j) {
      int srow = qs + lg * 4 + j;
      ao[(size_t)srow * DMODEL + h * HD + dt * 16 + ll] = f2bf(o[dt][j] * rdsj[j]);
    }
  }
}

// ---------------- launch ----------------

extern "C" void kernel_launch(void* const* d_in, const int* in_sizes, int n_in,
                              void* d_out, int out_size, void* d_ws, size_t ws_size,
                              hipStream_t stream) {
  const float* x = (const float*)d_in[0];
  const float* Wq = (const float*)d_in[1];
  const float* Wk = (const float*)d_in[2];
  const float* Wv = (const float*)d_in[3];
  const float* Wo = (const float*)d_in[4];
  const float* lam = (const float*)d_in[5];
  float* out = (float*)d_out;

  char* ws = (char*)d_ws;
  u16* xb = (u16*)(ws);                               // 8 MB  [2048][2048]
  u16* WT = (u16*)(ws + (8u << 20));                  // 12 MB [3072][2048] (Wq^T|Wk^T|Wv^T)
  u16* WoT = (u16*)(ws + (20u << 20));                // 8 MB  [2048][2048]
  u16* qr = (u16*)(ws + (28u << 20));                 // 8 MB  [16][2048][128]
  u16* kr = (u16*)(ws + (36u << 20));                 // 2 MB  [4][2048][128]
  u16* vt = (u16*)(ws + (38u << 20));                 // 2 MB  [4][128][2048]
  u16* ao = (u16*)(ws + (40u << 20));                 // 8 MB  [2048][2048]
  float2* cs = (float2*)(ws + (48u << 20));           // 1 MB  [2048][64]

  k_rope_table<<<S_LEN, 64, 0, stream>>>(cs);
  k_prep<<<14336, 256, 0, stream>>>(x, xb, Wq, Wk, Wv, Wo, WT, WoT);

  k_gemm<0><<<dim3(32, 24), 256, 0, stream>>>(xb, WT, nullptr, 2048, 3072, qr, kr, vt);

  // K roped in-place; Q-rope (+QSCALE, exp2-domain fold) fused into k_attn
  k_rope_k<<<(NKV * S_LEN * 64) / 256, 256, 0, stream>>>(kr, cs);

  k_attn<<<dim3(S_LEN / 64, NH), 256, 0, stream>>>(qr, kr, vt, lam, cs, ao);

  k_gemm<1><<<dim3(32, 16), 256, 0, stream>>>(ao, WoT, out, 2048, 2048, nullptr, nullptr, nullptr);
}

// Round 9
// 115.882 us; speedup vs baseline: 1.5848x; 1.0364x over previous
//
#include <hip/hip_runtime.h>

typedef unsigned int u32;
typedef unsigned short u16;
typedef __attribute__((ext_vector_type(4))) float f32x4;
typedef __attribute__((ext_vector_type(8))) short s16x8;

#define S_LEN 2048
#define DMODEL 2048
#define NH 16
#define NKV 4
#define HD 128
#define WIN 512
// 0.125 (1/sqrt(64)) * log2(e): folds score scale + exp2-domain conversion into Q
#define QSCALE 0.18033688011112042f

#define WAIT_VMCNT4 asm volatile("s_waitcnt vmcnt(4)" ::: "memory")
#define WAIT_VMCNT0 asm volatile("s_waitcnt vmcnt(0)" ::: "memory")

__device__ __forceinline__ u16 f2bf(float f) {
  union { float f; u32 u; } v; v.f = f;
  u32 r = v.u + 0x7FFFu + ((v.u >> 16) & 1u);
  return (u16)(r >> 16);
}
__device__ __forceinline__ float bf2f(u16 h) {
  union { u32 u; float f; } v; v.u = ((u32)h) << 16;
  return v.f;
}

__device__ __forceinline__ void async16(const void* g, void* l) {
  __builtin_amdgcn_global_load_lds((const __attribute__((address_space(1))) void*)g,
                                   (__attribute__((address_space(3))) void*)l, 16, 0, 0);
}

// ---------------- prep kernel ----------------
// bid < 4096: x f32->bf16 convert. 4096..14336: weight transposes
// (Wq 4096 | Wk 1024 | Wv 1024 | Wo 4096). >=14336: rope cos/sin table.
__global__ __launch_bounds__(256) void k_prep(const float* __restrict__ x, u16* __restrict__ xb,
                                              const float* __restrict__ Wq,
                                              const float* __restrict__ Wk,
                                              const float* __restrict__ Wv,
                                              const float* __restrict__ Wo,
                                              u16* __restrict__ WT, u16* __restrict__ WoT,
                                              float2* __restrict__ cs) {
  __shared__ float tile[32][33];
  const int bid = blockIdx.x;
  if (bid >= 14336) {  // rope table: 512 blocks x 4 s-rows x 64 d
    int s = (bid - 14336) * 4 + (threadIdx.x >> 6);
    int d = threadIdx.x & 63;
    float invf = expf(-((float)(2 * d) / (float)HD) * logf(10000.0f));
    float fr = (float)s * invf;
    float sv, cv;
    sincosf(fr, &sv, &cv);
    cs[s * 64 + d] = make_float2(cv, sv);
    return;
  }
  if (bid < 4096) {
    int i = bid * 256 + threadIdx.x;
    float4 v = ((const float4*)x)[i];
    ushort4 o;
    o.x = f2bf(v.x); o.y = f2bf(v.y); o.z = f2bf(v.z); o.w = f2bf(v.w);
    ((ushort4*)xb)[i] = o;
    return;
  }
  const int b = bid - 4096;
  const float* src;
  u16* dst;
  int N, nt, kt;
  if (b < 4096) {
    src = Wq; dst = WT; N = 2048; nt = b & 63; kt = b >> 6;
  } else if (b < 5120) {
    int i = b - 4096;
    src = Wk; dst = WT + (size_t)2048 * 2048; N = 512; nt = i & 15; kt = i >> 4;
  } else if (b < 6144) {
    int i = b - 5120;
    src = Wv; dst = WT + (size_t)2560 * 2048; N = 512; nt = i & 15; kt = i >> 4;
  } else {
    int i = b - 6144;
    src = Wo; dst = WoT; N = 2048; nt = i & 63; kt = i >> 6;
  }
  const int tx = threadIdx.x & 31, ty = threadIdx.x >> 5;
  const int n0 = nt * 32, k0 = kt * 32;
#pragma unroll
  for (int i = 0; i < 4; ++i)
    tile[ty + 8 * i][tx] = src[(size_t)(k0 + ty + 8 * i) * N + n0 + tx];
  __syncthreads();
#pragma unroll
  for (int i = 0; i < 4; ++i)
    dst[(size_t)(n0 + ty + 8 * i) * 2048 + k0 + tx] = f2bf(tile[tx][ty + 8 * i]);
}

// rope in-place on kr only (Q-rope fused into k_attn). grid exact: 2048 blocks.
__global__ void k_rope_k(u16* __restrict__ kr, const float2* __restrict__ cs) {
  int i = blockIdx.x * blockDim.x + threadIdx.x;
  int rowg = i >> 6, d = i & 63;
  int s = rowg & (S_LEN - 1);
  float2 c = cs[s * 64 + d];
  u16* p = kr + (size_t)rowg * HD;
  float a = bf2f(p[d]), b = bf2f(p[d + 64]);
  p[d]      = f2bf(a * c.x - b * c.y);
  p[d + 64] = f2bf(b * c.x + a * c.y);
}

// ---------------- GEMM ----------------
// A [M][K] bf16 row-major, BT [N][K] bf16. 64x128 tile, BK=64, 4 waves (2x2 of
// 32x64), double-buffered LDS (T3-min), chunked XCD swizzle.
// MODE 0: scatter epilogue -> qr[h][s][d], kr[h][s][d], vt[h][d][s]
// MODE 1: plain fp32 C[M][N]

template <int MODE>
__global__ __launch_bounds__(256) void k_gemm(const u16* __restrict__ A, const u16* __restrict__ BT,
                                              float* __restrict__ Cf, int K, int N,
                                              u16* __restrict__ qr, u16* __restrict__ kr,
                                              u16* __restrict__ vt) {
  // A rows 0..63, B rows 64..191; each row 64 u16 = 128B; 24KB per buffer
  __shared__ u16 S[2][192 * 64];
  const int t = threadIdx.x;
  const int l = t & 63, w = t >> 6;
  const int lg = l >> 4, ll = l & 15;

  // chunked XCD swizzle (bijective: nwg % 8 == 0 for both call sites)
  const u32 nwg = gridDim.x * gridDim.y;
  const u32 bid = blockIdx.y * gridDim.x + blockIdx.x;  // m-fastest linearization
  const u32 sid = (bid & 7u) * (nwg >> 3) + (bid >> 3);
  const int m0 = (int)(sid % gridDim.x) * 64;
  const int n0 = (int)(sid / gridDim.x) * 128;

  const int wm = (w >> 1) * 32, wn = (w & 1) * 64;

  const u16* gp[6];
  u32 lo[6];
#pragma unroll
  for (int j = 0; j < 6; ++j) {
    u32 u = (u32)t * 16u + (u32)j * 4096u;
    u32 row = u >> 7;
    u32 slot = ((u >> 4) & 7u) ^ (row & 7u);
    lo[j] = u;
    gp[j] = (row < 64 ? A + (size_t)(m0 + (int)row) * K
                      : BT + (size_t)(n0 + (int)(row - 64)) * K) + slot * 8;
  }
  auto stage = [&](int b, int k0) {
#pragma unroll
    for (int j = 0; j < 6; ++j) async16(gp[j] + k0, (char*)S[b] + lo[j]);
  };

  f32x4 acc[2][4];
#pragma unroll
  for (int i = 0; i < 2; ++i)
#pragma unroll
    for (int j = 0; j < 4; ++j) acc[i][j] = (f32x4){0.f, 0.f, 0.f, 0.f};

  stage(0, 0);
  __syncthreads();

  const int nit = K / 64;
#pragma unroll 2
  for (int it = 0; it < nit; ++it) {
    const int cur = it & 1;
    if (it + 1 < nit) stage(cur ^ 1, (it + 1) * 64);  // loads fly under compute

    s16x8 af[2][2], bq[4][2];
#pragma unroll
    for (int mt = 0; mt < 2; ++mt) {
      u32 r = (u32)(wm + mt * 16 + ll);
#pragma unroll
      for (int ks = 0; ks < 2; ++ks)
        af[mt][ks] = *(const s16x8*)((const char*)S[cur] + r * 128u +
                                     ((((u32)(ks * 4 + lg)) ^ (r & 7u)) * 16u));
    }
#pragma unroll
    for (int nt = 0; nt < 4; ++nt) {
      u32 r = (u32)(64 + wn + nt * 16 + ll);
#pragma unroll
      for (int ks = 0; ks < 2; ++ks)
        bq[nt][ks] = *(const s16x8*)((const char*)S[cur] + r * 128u +
                                     ((((u32)(ks * 4 + lg)) ^ (r & 7u)) * 16u));
    }
#pragma unroll
    for (int ks = 0; ks < 2; ++ks)
#pragma unroll
      for (int mt = 0; mt < 2; ++mt)
#pragma unroll
        for (int nt = 0; nt < 4; ++nt)
          acc[mt][nt] = __builtin_amdgcn_mfma_f32_16x16x32_bf16(af[mt][ks], bq[nt][ks],
                                                                acc[mt][nt], 0, 0, 0);
    __syncthreads();
  }

  if (MODE == 1) {
#pragma unroll
    for (int mt = 0; mt < 2; ++mt) {
      int srow = m0 + wm + mt * 16 + lg * 4;
#pragma unroll
      for (int nt = 0; nt < 4; ++nt) {
        int col = n0 + wn + nt * 16 + ll;
        f32x4 a = acc[mt][nt];
#pragma unroll
        for (int j = 0; j < 4; ++j) Cf[(size_t)(srow + j) * N + col] = a[j];
      }
    }
  } else {
#pragma unroll
    for (int nt = 0; nt < 4; ++nt) {
      int cb = n0 + wn + nt * 16;  // wave-uniform
#pragma unroll
      for (int mt = 0; mt < 2; ++mt) {
        int srow = m0 + wm + mt * 16 + lg * 4;
        f32x4 a = acc[mt][nt];
        if (cb < 2048) {
          int hh = cb >> 7, d = (cb & 127) + ll;
          u16* p = qr + ((size_t)hh * S_LEN) * HD + d;
#pragma unroll
          for (int j = 0; j < 4; ++j) p[(size_t)(srow + j) * HD] = f2bf(a[j]);
        } else if (cb < 2560) {
          int hh = (cb - 2048) >> 7, d = ((cb - 2048) & 127) + ll;
          u16* p = kr + ((size_t)hh * S_LEN) * HD + d;
#pragma unroll
          for (int j = 0; j < 4; ++j) p[(size_t)(srow + j) * HD] = f2bf(a[j]);
        } else {
          int hh = (cb - 2560) >> 7, d = ((cb - 2560) & 127) + ll;
          ushort4 pk;
          pk.x = f2bf(a[0]); pk.y = f2bf(a[1]); pk.z = f2bf(a[2]); pk.w = f2bf(a[3]);
          *(ushort4*)(vt + ((size_t)hh * HD + d) * S_LEN + srow) = pk;
        }
      }
    }
  }
}

// ---------------- attention ----------------
// Head-sharing grid: block = 16 q rows x ALL 4 heads of one KV group
// (grid (S/16, NKV), wave w = head hkv*4+w). All waves share one key window
// [kbeg, qs+15] -> zero wave-idle chunks, uniform masks, K/V staged once for
// 4 heads. 3-buffer counted-vmcnt pipeline in both passes (2-ahead, stage
// issued AFTER barrier; buffer distance 2 is race-free: readers of buf
// (tc+2)%3 finished at barrier(tc)). LDS 53KB -> 3 blocks/CU (12 waves/CU).
// Pass 1: K-only 64-key tiles. Pass 2: 32-key tiles, buf = K(8KB)+V(8KB).
// Q-RoPE (+QSCALE exp2-domain fold) in-register. No-max exp2 softmax.
__global__ __launch_bounds__(256, 3) void k_attn(const u16* __restrict__ qr,
                                                 const u16* __restrict__ kr,
                                                 const u16* __restrict__ vt,
                                                 const float* __restrict__ lam,
                                                 const float2* __restrict__ cs,
                                                 u16* __restrict__ ao) {
  __shared__ u16 KV[3][8192];   // 3 x 16KB
  __shared__ u16 P[4][16 * 40]; // per-wave P^T tile, row stride 40 u16 (80B)
  const int t = threadIdx.x;
  const int l = t & 63, w = t >> 6;
  const int lg = l >> 4, ll = l & 15;
  const int hkv = blockIdx.y;
  const int h = hkv * 4 + w;        // this wave's head
  const int qs = blockIdx.x * 16;   // block-shared q range [qs, qs+16)
  const int row = qs + ll;          // this lane's q row (same for all waves)

  const u16* Qp = qr + ((size_t)h * S_LEN + qs) * HD;
  const u16* Kp = kr + (size_t)hkv * S_LEN * HD;
  const u16* Vp = vt + (size_t)hkv * HD * S_LEN;

  const int kbeg = (qs >= 512) ? ((qs - 511) & ~63) : 0;
  const int nch1 = (qs + 15 - kbeg) / 64 + 1;  // 64-key chunks (pass 1)
  const int nch2 = (qs + 15 - kbeg) / 32 + 1;  // 32-key chunks (pass 2)

  // pass-1 staging coords (16KB tile: 64 rows x 256B, 16 slots, slot ^= row&7)
  u32 ku1[4], kr1[4], ks1[4];
#pragma unroll
  for (int j = 0; j < 4; ++j) {
    u32 u = (u32)t * 16u + (u32)j * 4096u;
    ku1[j] = u;
    kr1[j] = u >> 8;
    ks1[j] = ((u >> 4) & 15u) ^ (kr1[j] & 7u);
  }
  // pass-2 K coords (8KB: 32 rows x 256B) and V coords (8KB: 64 LDS rows x
  // 128B; LDS row r = d rows 2r,2r+1; logical slot = phys ^ (r&7))
  u32 ku2[2], kr2[2], ks2[2], vu2[2], vd2[2], vk2[2];
#pragma unroll
  for (int j = 0; j < 2; ++j) {
    u32 u = (u32)t * 16u + (u32)j * 4096u;
    ku2[j] = u;
    kr2[j] = u >> 8;
    ks2[j] = ((u >> 4) & 15u) ^ (kr2[j] & 7u);
    u32 r = u >> 7;
    u32 lgc = ((u >> 4) & 7u) ^ (r & 7u);
    vu2[j] = u;
    vd2[j] = 2u * r + (lgc >> 2);
    vk2[j] = (lgc & 3u) * 8u;
  }

  auto stage1 = [&](int buf, int tcc) {
    const int c = kbeg + tcc * 64;
    char* dst = (char*)KV + (size_t)buf * 16384;
#pragma unroll
    for (int j = 0; j < 4; ++j)
      async16(Kp + (size_t)(c + kr1[j]) * HD + ks1[j] * 8, dst + ku1[j]);
  };
  auto stage2 = [&](int buf, int tcc) {
    const int c = kbeg + tcc * 32;
    char* dst = (char*)KV + (size_t)buf * 16384;
#pragma unroll
    for (int j = 0; j < 2; ++j) {
      async16(Kp + (size_t)(c + kr2[j]) * HD + ks2[j] * 8, dst + ku2[j]);
      async16(Vp + (size_t)vd2[j] * S_LEN + c + vk2[j], dst + 8192 + vu2[j]);
    }
  };

  // ---- Q fragments + in-register RoPE (+QSCALE) ----
  s16x8 qa[4];
#pragma unroll
  for (int i = 0; i < 4; ++i)
    qa[i] = *(const s16x8*)(Qp + (size_t)ll * HD + i * 32 + lg * 8);
  {
    const float4* cp4 = (const float4*)(cs + (size_t)row * 64);  // 32 float4/row
#pragma unroll
    for (int i = 0; i < 2; ++i) {
      float4 cv[4];
#pragma unroll
      for (int jj = 0; jj < 4; ++jj) cv[jj] = cp4[i * 16 + lg * 4 + jj];
      s16x8 lo = qa[i], hi = qa[i + 2];
#pragma unroll
      for (int j = 0; j < 8; ++j) {
        float cc = (j & 1) ? cv[j >> 1].z : cv[j >> 1].x;
        float ss = (j & 1) ? cv[j >> 1].w : cv[j >> 1].y;
        float a = bf2f((u16)lo[j]), b = bf2f((u16)hi[j]);
        lo[j] = (short)f2bf((a * cc - b * ss) * QSCALE);
        hi[j] = (short)f2bf((b * cc + a * ss) * QSCALE);
      }
      qa[i] = lo; qa[i + 2] = hi;
    }
  }

  const f32x4 zero = {0.f, 0.f, 0.f, 0.f};
  float z1 = 0.f, z2 = 0.f;

  // ---- pass 1: Z sums (3-buf K, counted vmcnt, 2-ahead) ----
  stage1(0, 0);
  stage1(1, (nch1 > 1) ? 1 : 0);

  for (int tc = 0; tc < nch1; ++tc) {
    WAIT_VMCNT4;                    // own stage tc landed (in-order vmem)
    __builtin_amdgcn_s_barrier();   // all waves' stage tc landed
    {
      int ci = tc + 2; if (ci > nch1 - 1) ci = nch1 - 1;  // clamped, uniform
      stage1((tc + 2) % 3, ci);
    }
    const int c = kbeg + tc * 64;
    const u16* Kb = (const u16*)((const char*)KV + (size_t)(tc % 3) * 16384);
    float acc1 = 0.f, acc2 = 0.f;
#pragma unroll
    for (int kt = 0; kt < 4; ++kt) {
      const int kbase = c + kt * 16;
      if (kbase > qs + 15 || kbase + 15 < qs - (WIN - 1)) continue;  // uniform
      const int kr_ = kt * 16 + ll;
      const u16* kp = Kb + kr_ * 128;
      const u32 sw = (u32)(kr_ & 7);
      s16x8 b0 = *(const s16x8*)(kp + ((lg ^ sw) * 8));
      s16x8 b1 = *(const s16x8*)(kp + (((4 + lg) ^ sw) * 8));
      s16x8 b2 = *(const s16x8*)(kp + (((8 + lg) ^ sw) * 8));
      s16x8 b3 = *(const s16x8*)(kp + (((12 + lg) ^ sw) * 8));
      f32x4 a = __builtin_amdgcn_mfma_f32_16x16x32_bf16(b0, qa[0], zero, 0, 0, 0);
      a = __builtin_amdgcn_mfma_f32_16x16x32_bf16(b1, qa[1], a, 0, 0, 0);
      f32x4 b = __builtin_amdgcn_mfma_f32_16x16x32_bf16(b2, qa[2], zero, 0, 0, 0);
      b = __builtin_amdgcn_mfma_f32_16x16x32_bf16(b3, qa[3], b, 0, 0, 0);
      const bool fullk = (kbase + 15 <= qs) && (kbase >= qs - 496);
      if (!fullk) {
#pragma unroll
        for (int j = 0; j < 4; ++j) {
          int key = kbase + lg * 4 + j;
          bool ok = (key <= row) && (key > row - WIN);
          a[j] = ok ? a[j] : -1e30f;
          b[j] = ok ? b[j] : -1e30f;
        }
      }
#pragma unroll
      for (int j = 0; j < 4; ++j) {
        acc1 += __builtin_amdgcn_exp2f(a[j]);  // exp2(-1e30) flushes to 0
        acc2 += __builtin_amdgcn_exp2f(b[j]);
      }
    }
    z1 += acc1; z2 += acc2;
  }

  // merge the 4 lg-group partials (lanes ll, ll+16, ll+32, ll+48 share q=ll)
  z1 += __shfl_xor(z1, 16, 64); z1 += __shfl_xor(z1, 32, 64);
  z2 += __shfl_xor(z2, 16, 64); z2 += __shfl_xor(z2, 32, 64);
  const float l2z1 = __builtin_amdgcn_logf(z1);  // v_log_f32 = log2
  const float l2z2 = __builtin_amdgcn_logf(z2);
  const float lm = lam[h];

  // ---- pass 2: diff-combine + PV (3-buf K8+V8, counted vmcnt, 2-ahead) ----
  f32x4 o[8];
#pragma unroll
  for (int dt = 0; dt < 8; ++dt) o[dt] = zero;
  float dsum = 0.f;
  u16* Pw = &P[w][0];

  WAIT_VMCNT0;      // pass-1 trailing stages landed
  __syncthreads();  // all waves done with pass-1 buffers

  stage2(0, 0);
  stage2(1, (nch2 > 1) ? 1 : 0);

  for (int tc = 0; tc < nch2; ++tc) {
    WAIT_VMCNT4;                    // own stage tc landed
    __builtin_amdgcn_s_barrier();   // all waves' stage tc landed
    {
      int ci = tc + 2; if (ci > nch2 - 1) ci = nch2 - 1;  // clamped, uniform
      stage2((tc + 2) % 3, ci);
    }
    const int c = kbeg + tc * 32;
    const u16* Kb = (const u16*)((const char*)KV + (size_t)(tc % 3) * 16384);
    const u16* Vb = Kb + 4096;  // +8KB
    const bool full = (c + 31 <= qs) && (c >= qs - 496);
    __builtin_amdgcn_s_setprio(1);
#pragma unroll
    for (int kt = 0; kt < 2; ++kt) {
      const int kr_ = kt * 16 + ll;
      const u16* kp = Kb + kr_ * 128;
      const u32 sw = (u32)(kr_ & 7);
      s16x8 b0 = *(const s16x8*)(kp + ((lg ^ sw) * 8));
      s16x8 b1 = *(const s16x8*)(kp + (((4 + lg) ^ sw) * 8));
      s16x8 b2 = *(const s16x8*)(kp + (((8 + lg) ^ sw) * 8));
      s16x8 b3 = *(const s16x8*)(kp + (((12 + lg) ^ sw) * 8));
      f32x4 a = __builtin_amdgcn_mfma_f32_16x16x32_bf16(b0, qa[0], zero, 0, 0, 0);
      a = __builtin_amdgcn_mfma_f32_16x16x32_bf16(b1, qa[1], a, 0, 0, 0);
      f32x4 b = __builtin_amdgcn_mfma_f32_16x16x32_bf16(b2, qa[2], zero, 0, 0, 0);
      b = __builtin_amdgcn_mfma_f32_16x16x32_bf16(b3, qa[3], b, 0, 0, 0);
      if (!full) {
#pragma unroll
        for (int j = 0; j < 4; ++j) {
          int key = c + kt * 16 + lg * 4 + j;
          bool ok = (key <= row) && (key > row - WIN);
          a[j] = ok ? a[j] : -1e30f;
          b[j] = ok ? b[j] : -1e30f;
        }
      }
      float d4[4];
#pragma unroll
      for (int j = 0; j < 4; ++j) {
        float a1 = __builtin_amdgcn_exp2f(a[j] - l2z1);
        float a2 = __builtin_amdgcn_exp2f(b[j] - l2z2);
        float d = fmaxf(fmaf(-lm, a2, a1), 0.f);
        d4[j] = d;
        dsum += d;
      }
      u32 p01, p23;
      asm("v_cvt_pk_bf16_f32 %0, %1, %2" : "=v"(p01) : "v"(d4[0]), "v"(d4[1]));
      asm("v_cvt_pk_bf16_f32 %0, %1, %2" : "=v"(p23) : "v"(d4[2]), "v"(d4[3]));
      uint2 pk; pk.x = p01; pk.y = p23;
      *(uint2*)(&Pw[ll * 40 + kt * 16 + lg * 4]) = pk;
    }
    // per-wave LDS transpose round-trip (wave-synchronous; compiler waits lgkm)
    s16x8 pf = *(const s16x8*)(&Pw[ll * 40 + lg * 8]);
#pragma unroll
    for (int dt = 0; dt < 8; ++dt) {
      const int d = dt * 16 + ll;
      const u32 r = (u32)(d >> 1);
      const u32 phys = ((u32)((d & 1) * 4 + lg)) ^ (r & 7u);
      s16x8 vf = *(const s16x8*)(Vb + r * 64 + phys * 8);
      o[dt] = __builtin_amdgcn_mfma_f32_16x16x32_bf16(pf, vf, o[dt], 0, 0, 0);
    }
    __builtin_amdgcn_s_setprio(0);
  }
  WAIT_VMCNT0;  // drain trailing stages before kernel end

  // dsum: merge lg partials, then fetch 1/(sum+eps) for output rows lg*4+j
  dsum += __shfl_xor(dsum, 16, 64);
  dsum += __shfl_xor(dsum, 32, 64);
  const float rds = __builtin_amdgcn_rcpf(dsum + 1e-6f);
  float rdsj[4];
#pragma unroll
  for (int j = 0; j < 4; ++j) rdsj[j] = __shfl(rds, lg * 4 + j, 64);

#pragma unroll
  for (int dt = 0; dt < 8; ++dt) {
#pragma unroll
    for (int j = 0; j < 4; ++j) {
      int srow = qs + lg * 4 + j;
      ao[(size_t)srow * DMODEL + h * HD + dt * 16 + ll] = f2bf(o[dt][j] * rdsj[j]);
    }
  }
}

// ---------------- launch ----------------

extern "C" void kernel_launch(void* const* d_in, const int* in_sizes, int n_in,
                              void* d_out, int out_size, void* d_ws, size_t ws_size,
                              hipStream_t stream) {
  const float* x = (const float*)d_in[0];
  const float* Wq = (const float*)d_in[1];
  const float* Wk = (const float*)d_in[2];
  const float* Wv = (const float*)d_in[3];
  const float* Wo = (const float*)d_in[4];
  const float* lam = (const float*)d_in[5];
  float* out = (float*)d_out;

  char* ws = (char*)d_ws;
  u16* xb = (u16*)(ws);                               // 8 MB  [2048][2048]
  u16* WT = (u16*)(ws + (8u << 20));                  // 12 MB [3072][2048] (Wq^T|Wk^T|Wv^T)
  u16* WoT = (u16*)(ws + (20u << 20));                // 8 MB  [2048][2048]
  u16* qr = (u16*)(ws + (28u << 20));                 // 8 MB  [16][2048][128]
  u16* kr = (u16*)(ws + (36u << 20));                 // 2 MB  [4][2048][128]
  u16* vt = (u16*)(ws + (38u << 20));                 // 2 MB  [4][128][2048]
  u16* ao = (u16*)(ws + (40u << 20));                 // 8 MB  [2048][2048]
  float2* cs = (float2*)(ws + (48u << 20));           // 1 MB  [2048][64]

  k_prep<<<14848, 256, 0, stream>>>(x, xb, Wq, Wk, Wv, Wo, WT, WoT, cs);

  k_gemm<0><<<dim3(32, 24), 256, 0, stream>>>(xb, WT, nullptr, 2048, 3072, qr, kr, vt);

  // K roped in-place; Q-rope (+QSCALE, exp2-domain fold) fused into k_attn
  k_rope_k<<<(NKV * S_LEN * 64) / 256, 256, 0, stream>>>(kr, cs);

  k_attn<<<dim3(S_LEN / 16, NKV), 256, 0, stream>>>(qr, kr, vt, lam, cs, ao);

  k_gemm<1><<<dim3(32, 16), 256, 0, stream>>>(ao, WoT, out, 2048, 2048, nullptr, nullptr, nullptr);
}